// Round 1
// baseline (10861.881 us; speedup 1.0000x reference)
//
#include <hip/hip_runtime.h>
#include <cfloat>
#include <cmath>

#define B_      8
#define NT_     257
#define DIM_    768
#define HEADS_  12
#define DH_     64
#define DEPTH_  6
#define NTOK_   515        // brain(257) + time(1) + image(257)
#define NKEY_   516        // + null kv
#define NROW_   (B_*NTOK_) // 4120
#define FFI_    3072

// ---------------- wave reductions (wave64) ----------------
__device__ __forceinline__ float wsum(float v){
#pragma unroll
  for (int o=32;o;o>>=1) v += __shfl_xor(v,o);
  return v;
}
__device__ __forceinline__ float wmax(float v){
#pragma unroll
  for (int o=32;o;o>>=1) v = fmaxf(v,__shfl_xor(v,o));
  return v;
}

// ---------------- time-embedding MLP (one block per batch) ----------------
__global__ __launch_bounds__(256) void time_mlp(const int* __restrict__ ts,
    const float* __restrict__ w1, const float* __restrict__ b1,
    const float* __restrict__ w2, const float* __restrict__ b2,
    const float* __restrict__ w3, const float* __restrict__ b3,
    float* __restrict__ temb){
  __shared__ float pe[768];
  __shared__ float h1[1536];
  __shared__ float h2[1536];
  int b = blockIdx.x;
  float t = (float)ts[b];
  int tid = threadIdx.x;
  const float c = -logf(10000.0f)/383.0f;   // half-1 = 383
  for (int i=tid;i<768;i+=256){
    int k = (i<384)? i : i-384;
    float f = __expf((float)k * c);
    pe[i] = (i<384)? sinf(t*f) : cosf(t*f);
  }
  __syncthreads();
  for (int j=tid;j<1536;j+=256){
    float a=b1[j];
    for (int k=0;k<768;++k) a += pe[k]*w1[(size_t)k*1536+j];
    h1[j]= a/(1.0f+__expf(-a));
  }
  __syncthreads();
  for (int j=tid;j<1536;j+=256){
    float a=b2[j];
    for (int k=0;k<1536;++k) a += h1[k]*w2[(size_t)k*1536+j];
    h2[j]= a/(1.0f+__expf(-a));
  }
  __syncthreads();
  for (int j=tid;j<768;j+=256){
    float a=b3[j];
    for (int k=0;k<1536;++k) a += h2[k]*w3[(size_t)k*768+j];
    temb[(size_t)b*768+j]=a;
  }
}

// ---------------- build token sequence ----------------
__global__ __launch_bounds__(256) void build_tokens(const float* __restrict__ brain,
    const float* __restrict__ image, const float* __restrict__ lq,
    const float* __restrict__ temb, float* __restrict__ x){
  int row = blockIdx.x;         // b*515 + t
  int b = row / NTOK_, t = row % NTOK_;
  int tid = threadIdx.x;
#pragma unroll
  for (int u=0;u<3;++u){
    int d = tid + u*256;
    float val;
    if (t < 257)      val = brain[((size_t)(b*257+t))*DIM_ + d];
    else if (t == 257) val = temb[(size_t)b*DIM_ + d];
    else               val = image[((size_t)(b*257 + (t-258)))*DIM_ + d] + lq[((size_t)(t-258))*DIM_ + d];
    x[(size_t)row*DIM_ + d] = val;
  }
}

// ---------------- relative position bias table: bias[h][i][j] ----------------
__global__ __launch_bounds__(256) void bias_fill(const float* __restrict__ emb, float* __restrict__ bias){
  int i = blockIdx.x;  // 0..514
  for (int j=threadIdx.x; j<NKEY_; j+=256){
    int nrel = i - j; if (nrel < 0) nrel = 0;
    int bucket;
    if (nrel < 16) bucket = nrel;
    else {
      int large = 16 + (int)(logf((float)nrel * (1.0f/16.0f)) / logf(8.0f) * 16.0f);
      bucket = large < 31 ? large : 31;
    }
    for (int h=0; h<HEADS_; ++h)
      bias[((size_t)h*NTOK_ + i)*NKEY_ + j] = emb[bucket*HEADS_ + h];
  }
}

// ---------------- LayerNorm (block per row). resid!=null -> dst = resid + LN(src) ----------------
__global__ __launch_bounds__(256) void ln_kernel(const float* __restrict__ src, const float* __restrict__ gamma,
    const float* __restrict__ resid, float* __restrict__ dst, int stable){
  __shared__ float red[4];
  int row = blockIdx.x;
  const float* s = src + (size_t)row*DIM_;
  int tid = threadIdx.x, wv = tid>>6, ln = tid&63;
  float v0 = s[tid], v1 = s[tid+256], v2 = s[tid+512];
  if (stable){
    float m = wmax(fmaxf(fmaxf(v0,v1),v2));
    if (ln==0) red[wv]=m;
    __syncthreads();
    m = fmaxf(fmaxf(red[0],red[1]),fmaxf(red[2],red[3]));
    __syncthreads();
    float inv = 1.0f/m; v0*=inv; v1*=inv; v2*=inv;
  }
  float sum = wsum(v0+v1+v2);
  if (ln==0) red[wv]=sum;
  __syncthreads();
  sum = red[0]+red[1]+red[2]+red[3];
  __syncthreads();
  float mean = sum * (1.0f/DIM_);
  float d0=v0-mean, d1=v1-mean, d2=v2-mean;
  float sq = wsum(d0*d0+d1*d1+d2*d2);
  if (ln==0) red[wv]=sq;
  __syncthreads();
  sq = red[0]+red[1]+red[2]+red[3];
  float inv = rsqrtf(sq*(1.0f/DIM_) + 1e-5f);
  float o0 = d0*inv*gamma[tid];
  float o1 = d1*inv*gamma[tid+256];
  float o2 = d2*inv*gamma[tid+512];
  if (resid){
    const float* r = resid + (size_t)row*DIM_;
    o0 += r[tid]; o1 += r[tid+256]; o2 += r[tid+512];
  }
  float* d = dst + (size_t)row*DIM_;
  d[tid]=o0; d[tid+256]=o1; d[tid+512]=o2;
}

// ---------------- f32 GEMM: C[M,N] = A[M,K] @ B[K,N]; N%64==0, K%16==0 ----------------
__global__ __launch_bounds__(256) void gemm_f32(const float* __restrict__ A, const float* __restrict__ Bm,
    float* __restrict__ C, int M, int N, int K){
  __shared__ float As[16][65];
  __shared__ float Bs[16][64];
  int tid = threadIdx.x;
  int tx = tid & 15, ty = tid >> 4;
  int row0 = blockIdx.y*64, col0 = blockIdx.x*64;
  float acc[4][4] = {};
  int ar_l = tid >> 2;           // 0..63
  int ac_l = (tid & 3) << 2;     // 0,4,8,12
  int br_l = tid >> 4;           // 0..15
  int bc_l = (tid & 15) << 2;    // 0..60
  for (int k0=0;k0<K;k0+=16){
    int ar = row0 + ar_l;
    float4 av = make_float4(0,0,0,0);
    if (ar < M) av = *(const float4*)(A + (size_t)ar*K + k0 + ac_l);
    As[ac_l+0][ar_l]=av.x; As[ac_l+1][ar_l]=av.y; As[ac_l+2][ar_l]=av.z; As[ac_l+3][ar_l]=av.w;
    float4 bv = *(const float4*)(Bm + (size_t)(k0+br_l)*N + col0 + bc_l);
    *(float4*)&Bs[br_l][bc_l] = bv;
    __syncthreads();
#pragma unroll
    for (int kk=0;kk<16;++kk){
      float a[4], bb[4];
#pragma unroll
      for (int i=0;i<4;++i) a[i]=As[kk][ty*4+i];
#pragma unroll
      for (int j=0;j<4;++j) bb[j]=Bs[kk][tx*4+j];
#pragma unroll
      for (int i=0;i<4;++i)
#pragma unroll
        for (int j=0;j<4;++j) acc[i][j] += a[i]*bb[j];
    }
    __syncthreads();
  }
#pragma unroll
  for (int i=0;i<4;++i){
    int r = row0 + ty*4 + i;
    if (r < M)
      *(float4*)(C + (size_t)r*N + col0 + tx*4) = make_float4(acc[i][0],acc[i][1],acc[i][2],acc[i][3]);
  }
}

// ---------------- gated FF GEMM: U[M,3072] = (A@Win[:, :3072]) * silu(A@Win[:, 3072:]) ----------------
__global__ __launch_bounds__(256) void gemm_gated(const float* __restrict__ A, const float* __restrict__ Bm,
    float* __restrict__ C, int M, int K){
  const int N = FFI_, NFULL = 2*FFI_;
  __shared__ float As[16][65];
  __shared__ float Ba[16][64];
  __shared__ float Bg[16][64];
  int tid = threadIdx.x;
  int tx = tid & 15, ty = tid >> 4;
  int row0 = blockIdx.y*64, col0 = blockIdx.x*64;
  float acca[4][4] = {}, accg[4][4] = {};
  int ar_l = tid >> 2, ac_l = (tid & 3) << 2;
  int br_l = tid >> 4, bc_l = (tid & 15) << 2;
  for (int k0=0;k0<K;k0+=16){
    int ar = row0 + ar_l;
    float4 av = make_float4(0,0,0,0);
    if (ar < M) av = *(const float4*)(A + (size_t)ar*K + k0 + ac_l);
    As[ac_l+0][ar_l]=av.x; As[ac_l+1][ar_l]=av.y; As[ac_l+2][ar_l]=av.z; As[ac_l+3][ar_l]=av.w;
    float4 bva = *(const float4*)(Bm + (size_t)(k0+br_l)*NFULL + col0 + bc_l);
    float4 bvg = *(const float4*)(Bm + (size_t)(k0+br_l)*NFULL + FFI_ + col0 + bc_l);
    *(float4*)&Ba[br_l][bc_l] = bva;
    *(float4*)&Bg[br_l][bc_l] = bvg;
    __syncthreads();
#pragma unroll
    for (int kk=0;kk<16;++kk){
      float a[4], ba[4], bg[4];
#pragma unroll
      for (int i=0;i<4;++i) a[i]=As[kk][ty*4+i];
#pragma unroll
      for (int j=0;j<4;++j){ ba[j]=Ba[kk][tx*4+j]; bg[j]=Bg[kk][tx*4+j]; }
#pragma unroll
      for (int i=0;i<4;++i)
#pragma unroll
        for (int j=0;j<4;++j){ acca[i][j]+=a[i]*ba[j]; accg[i][j]+=a[i]*bg[j]; }
    }
    __syncthreads();
  }
#pragma unroll
  for (int i=0;i<4;++i){
    int r = row0 + ty*4 + i;
    if (r < M){
      float4 o;
      float g0=accg[i][0], g1=accg[i][1], g2=accg[i][2], g3=accg[i][3];
      o.x = acca[i][0]*(g0/(1.0f+__expf(-g0)));
      o.y = acca[i][1]*(g1/(1.0f+__expf(-g1)));
      o.z = acca[i][2]*(g2/(1.0f+__expf(-g2)));
      o.w = acca[i][3]*(g3/(1.0f+__expf(-g3)));
      *(float4*)(C + (size_t)r*N + col0 + tx*4) = o;
    }
  }
}

// ---------------- RoPE + l2norm + scale on q (layout b,n,h,d) ----------------
__global__ __launch_bounds__(256) void qprep(float* __restrict__ q){
  int vec = blockIdx.x*4 + (threadIdx.x>>6);
  int lane = threadIdx.x & 63;
  if (vec >= NROW_*HEADS_) return;
  int n = (vec/HEADS_) % NTOK_;
  float* p = q + (size_t)vec*DH_;
  float v = p[lane];
  float t1 = __shfl(v, lane & 62);
  float t2 = __shfl(v, lane | 1);
  float out = v;
  if (lane < 32){
    int ii = lane >> 1;
    float invf = __expf(-logf(10000.0f) * (float)ii / 16.0f);
    float fr = (float)n * invf;
    float c = cosf(fr), s = sinf(fr);
    out = (lane & 1) ? (t1*s + t2*c) : (t1*c - t2*s);
  }
  float sq = wsum(out*out);
  float nrm = fmaxf(sqrtf(sq), 1e-12f);
  p[lane] = out * (4.0f/nrm);
}

// ---------------- build k/v with null at j=0; RoPE+l2norm on k ----------------
__global__ __launch_bounds__(64) void kvprep(const float* __restrict__ kv, const float* __restrict__ nullkv,
    float* __restrict__ kcat, float* __restrict__ vcat){
  int bj = blockIdx.x;
  int b = bj / NKEY_, j = bj % NKEY_;
  int lane = threadIdx.x;
  float kl, vl;
  if (j == 0){ kl = nullkv[lane]; vl = nullkv[DH_+lane]; }
  else {
    const float* row = kv + (size_t)(b*NTOK_ + (j-1))*(2*DH_);
    kl = row[lane]; vl = row[DH_+lane];
  }
  float t1 = __shfl(kl, lane & 62);
  float t2 = __shfl(kl, lane | 1);
  if (j > 0 && lane < 32){
    int ii = lane >> 1;
    float invf = __expf(-logf(10000.0f) * (float)ii / 16.0f);
    float fr = (float)(j-1) * invf;
    float c = cosf(fr), s = sinf(fr);
    kl = (lane & 1) ? (t1*s + t2*c) : (t1*c - t2*s);
  }
  float sq = wsum(kl*kl);
  float nrm = fmaxf(sqrtf(sq), 1e-12f);
  kcat[((size_t)b*NKEY_+j)*DH_+lane] = kl*(4.0f/nrm);
  vcat[((size_t)b*NKEY_+j)*DH_+lane] = vl;
}

// ---------------- attention: one wave per (b,h,query-row) ----------------
__global__ __launch_bounds__(256) void attn_kernel(const float* __restrict__ q, const float* __restrict__ kcat,
    const float* __restrict__ vcat, const float* __restrict__ bias, float* __restrict__ o){
  int wave = threadIdx.x>>6, lane = threadIdx.x&63;
  int i = blockIdx.x*4 + wave;
  int h = blockIdx.y, b = blockIdx.z;
  if (i >= NTOK_) return;
  __shared__ float p_lds[4][NKEY_+4];
  __shared__ float q_lds[4][DH_];
  q_lds[wave][lane] = q[(((size_t)(b*NTOK_+i))*HEADS_ + h)*DH_ + lane];
  const float* kb = kcat + (size_t)b*NKEY_*DH_;
  const float* brow = bias + ((size_t)h*NTOK_ + i)*NKEY_;
  float mx = -INFINITY;
  for (int j0=0;j0<NKEY_;j0+=64){
    int j = j0 + lane;
    if (j < NKEY_){
      float s;
      if (j > i+1) s = -FLT_MAX;
      else {
        const float4* kr = (const float4*)(kb + (size_t)j*DH_);
        float acc = 0.f;
#pragma unroll
        for (int d4=0; d4<16; ++d4){
          float4 k4 = kr[d4];
          acc += q_lds[wave][d4*4+0]*k4.x + q_lds[wave][d4*4+1]*k4.y
               + q_lds[wave][d4*4+2]*k4.z + q_lds[wave][d4*4+3]*k4.w;
        }
        s = acc + brow[j];
      }
      p_lds[wave][j] = s;
      mx = fmaxf(mx, s);
    }
  }
  mx = wmax(mx);
  float sum = 0.f;
  for (int j0=0;j0<NKEY_;j0+=64){
    int j = j0 + lane;
    if (j < NKEY_){
      float p = __expf(p_lds[wave][j] - mx);
      p_lds[wave][j] = p;
      sum += p;
    }
  }
  sum = wsum(sum);
  float inv = 1.0f/sum;
  const float* vb = vcat + (size_t)b*NKEY_*DH_ + lane;
  int jend = i+2;            // exclusive; masked tail contributes 0
  float a0=0,a1=0,a2=0,a3=0;
  int j=0;
  for (; j+4<=jend; j+=4){
    a0 += p_lds[wave][j+0]*vb[(size_t)(j+0)*DH_];
    a1 += p_lds[wave][j+1]*vb[(size_t)(j+1)*DH_];
    a2 += p_lds[wave][j+2]*vb[(size_t)(j+2)*DH_];
    a3 += p_lds[wave][j+3]*vb[(size_t)(j+3)*DH_];
  }
  for (; j<jend; ++j) a0 += p_lds[wave][j]*vb[(size_t)j*DH_];
  o[(((size_t)(b*NTOK_+i))*HEADS_ + h)*DH_ + lane] = (a0+a1+a2+a3)*inv;
}

// ---------------- elementwise add ----------------
__global__ __launch_bounds__(256) void add_kernel(float* __restrict__ x, const float* __restrict__ t, int n){
  int i = blockIdx.x*blockDim.x + threadIdx.x;
  int stride = gridDim.x*blockDim.x;
  for (; i<n; i+=stride) x[i] += t[i];
}

// ---------------- gather last 257 tokens per batch ----------------
__global__ __launch_bounds__(256) void gather_rows(const float* __restrict__ src, float* __restrict__ dst){
  int m = blockIdx.x;              // 0..2055
  int b = m / NT_, t = m % NT_;
  const float* s = src + ((size_t)(b*NTOK_ + 258 + t))*DIM_;
  float* d = dst + (size_t)m*DIM_;
  for (int u=threadIdx.x; u<DIM_; u+=256) d[u] = s[u];
}

extern "C" void kernel_launch(void* const* d_in, const int* in_sizes, int n_in,
                              void* d_out, int out_size, void* d_ws, size_t ws_size,
                              hipStream_t stream) {
  const float* image = (const float*)d_in[0];
  const float* brain = (const float*)d_in[1];
  const int*   tsteps= (const int*)  d_in[2];
  const float* lq    = (const float*)d_in[3];
  const float* t_w1  = (const float*)d_in[4];
  const float* t_b1  = (const float*)d_in[5];
  const float* t_w2  = (const float*)d_in[6];
  const float* t_b2  = (const float*)d_in[7];
  const float* t_w3  = (const float*)d_in[8];
  const float* t_b3  = (const float*)d_in[9];
  const float* relpos= (const float*)d_in[10];
  const float* anorm = (const float*)d_in[11];
  const float* Wq    = (const float*)d_in[12];
  const float* Wkv   = (const float*)d_in[13];
  const float* nkv   = (const float*)d_in[14];
  const float* Wo    = (const float*)d_in[15];
  const float* aoutg = (const float*)d_in[16];
  const float* fng   = (const float*)d_in[17];
  const float* Win   = (const float*)d_in[18];
  const float* Wout  = (const float*)d_in[19];
  const float* fing  = (const float*)d_in[20];
  const float* Wproj = (const float*)d_in[21];
  float* out = (float*)d_out;

  float* ws   = (float*)d_ws;
  const size_t SZ_X = (size_t)NROW_*DIM_;        // 3,164,160
  float* x    = ws;
  float* xn   = x   + SZ_X;
  float* qb   = xn  + SZ_X;
  float* ob   = qb  + SZ_X;
  float* tb   = ob  + SZ_X;
  float* kvb  = tb  + SZ_X;                      // 4120*128
  float* kcat = kvb + (size_t)NROW_*128;         // 8*516*64
  float* vcat = kcat + (size_t)B_*NKEY_*DH_;
  float* bias = vcat + (size_t)B_*NKEY_*DH_;     // 12*515*516
  float* ub   = bias + (size_t)HEADS_*NTOK_*NKEY_; // 4120*3072
  float* temb = ub   + (size_t)NROW_*FFI_;       // 8*768
  float* gbuf = temb + (size_t)B_*DIM_;          // 2056*768

  time_mlp<<<B_,256,0,stream>>>(tsteps, t_w1,t_b1,t_w2,t_b2,t_w3,t_b3, temb);
  build_tokens<<<NROW_,256,0,stream>>>(brain, image, lq, temb, x);
  bias_fill<<<NTOK_,256,0,stream>>>(relpos, bias);

  for (int l=0; l<DEPTH_; ++l){
    ln_kernel<<<NROW_,256,0,stream>>>(x, anorm + (size_t)l*DIM_, nullptr, xn, 0);
    gemm_f32<<<dim3(DIM_/64,(NROW_+63)/64),256,0,stream>>>(xn, Wq + (size_t)l*DIM_*DIM_, qb, NROW_, DIM_, DIM_);
    gemm_f32<<<dim3(128/64,(NROW_+63)/64),256,0,stream>>>(xn, Wkv + (size_t)l*DIM_*128, kvb, NROW_, 128, DIM_);
    qprep<<<(NROW_*HEADS_+3)/4,256,0,stream>>>(qb);
    kvprep<<<B_*NKEY_,64,0,stream>>>(kvb, nkv + (size_t)l*2*DH_, kcat, vcat);
    attn_kernel<<<dim3((NTOK_+3)/4,HEADS_,B_),256,0,stream>>>(qb, kcat, vcat, bias, ob);
    gemm_f32<<<dim3(DIM_/64,(NROW_+63)/64),256,0,stream>>>(ob, Wo + (size_t)l*DIM_*DIM_, tb, NROW_, DIM_, DIM_);
    ln_kernel<<<NROW_,256,0,stream>>>(tb, aoutg + (size_t)l*DIM_, x, x, 0);
    ln_kernel<<<NROW_,256,0,stream>>>(x, fng + (size_t)l*DIM_, nullptr, xn, 0);
    gemm_gated<<<dim3(FFI_/64,(NROW_+63)/64),256,0,stream>>>(xn, Win + (size_t)l*DIM_*2*FFI_, ub, NROW_, DIM_);
    gemm_f32<<<dim3(DIM_/64,(NROW_+63)/64),256,0,stream>>>(ub, Wout + (size_t)l*FFI_*DIM_, tb, NROW_, DIM_, FFI_);
    add_kernel<<<2048,256,0,stream>>>(x, tb, NROW_*DIM_);
  }

  ln_kernel<<<NROW_,256,0,stream>>>(x, fing, nullptr, xn, 1);
  gather_rows<<<B_*NT_,256,0,stream>>>(xn, gbuf);
  gemm_f32<<<dim3(DIM_/64,(B_*NT_+63)/64),256,0,stream>>>(gbuf, Wproj, out, B_*NT_, DIM_, DIM_);
}

// Round 2
// 3047.452 us; speedup vs baseline: 3.5642x; 3.5642x over previous
//
#include <hip/hip_runtime.h>
#include <cfloat>
#include <cmath>

#define B_      8
#define NT_     257
#define DIM_    768
#define HEADS_  12
#define DH_     64
#define DEPTH_  6
#define NTOK_   515        // brain(257) + time(1) + image(257)
#define NKEY_   516        // + null kv
#define NROW_   (B_*NTOK_) // 4120
#define FFI_    3072

typedef unsigned short u16;
typedef __attribute__((ext_vector_type(8))) short short8;
typedef __attribute__((ext_vector_type(4))) float f32x4;

__device__ __forceinline__ u16 f2bf(float f){
  union { float f; unsigned u; } v; v.f = f;
  unsigned r = v.u + 0x7fffu + ((v.u >> 16) & 1u);
  return (u16)(r >> 16);
}
__device__ __forceinline__ float bf2f(u16 h){
  union { unsigned u; float f; } v; v.u = ((unsigned)h) << 16;
  return v.f;
}
__device__ __forceinline__ float wsum(float v){
#pragma unroll
  for (int o=32;o;o>>=1) v += __shfl_xor(v,o);
  return v;
}
__device__ __forceinline__ float wmax(float v){
#pragma unroll
  for (int o=32;o;o>>=1) v = fmaxf(v,__shfl_xor(v,o));
  return v;
}

// ---------------- transpose f32 [K][N] -> bf16 [N][K], batched over z ----------------
__global__ __launch_bounds__(256) void transpose_bf16(const float* __restrict__ src, u16* __restrict__ dst,
    int K, int N){
  __shared__ float tile[32][33];
  size_t zoff = (size_t)blockIdx.z * K * N;
  src += zoff; dst += zoff;
  int c0 = blockIdx.x*32, r0 = blockIdx.y*32;
  int tx = threadIdx.x & 31, ty = threadIdx.x >> 5;
#pragma unroll
  for (int u=0; u<4; ++u){
    int r = ty*4 + u;
    tile[r][tx] = src[(size_t)(r0 + r)*N + c0 + tx];
  }
  __syncthreads();
#pragma unroll
  for (int u=0; u<4; ++u){
    int r = ty*4 + u;
    dst[(size_t)(c0 + r)*K + r0 + tx] = f2bf(tile[tx][r]);
  }
}

// ---------------- time-embedding: pe + 3 fc layers ----------------
__global__ __launch_bounds__(256) void pe_kernel(const int* __restrict__ ts, float* __restrict__ pe){
  int b = blockIdx.x;
  float t = (float)ts[b];
  const float cc = -logf(10000.0f)/383.0f;
  for (int i=threadIdx.x; i<768; i+=256){
    int k = (i<384)? i : i-384;
    float f = __expf((float)k*cc);
    pe[b*768+i] = (i<384)? sinf(t*f) : cosf(t*f);
  }
}
__global__ __launch_bounds__(256) void fc_kernel(const float* __restrict__ in, const float* __restrict__ W,
    const float* __restrict__ bias, float* __restrict__ out, int K, int N, int act){
  extern __shared__ float in_lds[];
  for (int idx=threadIdx.x; idx<8*K; idx+=256) in_lds[idx] = in[idx];
  __syncthreads();
  int c = blockIdx.x*64 + (threadIdx.x & 63);
  int rg = threadIdx.x >> 6;
  float a0 = bias[c], a1 = a0;
  const float* i0 = in_lds + (size_t)(rg*2)*K;
  const float* i1 = i0 + K;
#pragma unroll 4
  for (int k=0; k<K; ++k){
    float w = W[(size_t)k*N + c];
    a0 += i0[k]*w; a1 += i1[k]*w;
  }
  if (act){ a0 = a0/(1.0f+__expf(-a0)); a1 = a1/(1.0f+__expf(-a1)); }
  out[(size_t)(rg*2)*N + c] = a0;
  out[(size_t)(rg*2+1)*N + c] = a1;
}

// ---------------- build token sequence (f32) ----------------
__global__ __launch_bounds__(256) void build_tokens(const float* __restrict__ brain,
    const float* __restrict__ image, const float* __restrict__ lq,
    const float* __restrict__ temb, float* __restrict__ x){
  int row = blockIdx.x;
  int b = row / NTOK_, t = row % NTOK_;
  int tid = threadIdx.x;
#pragma unroll
  for (int u=0;u<3;++u){
    int d = tid + u*256;
    float val;
    if (t < 257)      val = brain[((size_t)(b*257+t))*DIM_ + d];
    else if (t == 257) val = temb[(size_t)b*DIM_ + d];
    else               val = image[((size_t)(b*257 + (t-258)))*DIM_ + d] + lq[((size_t)(t-258))*DIM_ + d];
    x[(size_t)row*DIM_ + d] = val;
  }
}

// ---------------- rel-pos bias by delta: bias_d[h][delta], delta = clamp(i-j,0,514) ----------------
__global__ __launch_bounds__(256) void bias_delta(const float* __restrict__ emb, float* __restrict__ bias_d){
  int d = blockIdx.x*256 + threadIdx.x;
  if (d >= NTOK_) return;
  int bucket;
  if (d < 16) bucket = d;
  else {
    int lg = 16 + (int)(logf((float)d * (1.0f/16.0f)) * (16.0f/logf(8.0f)));
    bucket = lg < 31 ? lg : 31;
  }
  for (int h=0; h<HEADS_; ++h) bias_d[h*NTOK_ + d] = emb[bucket*HEADS_ + h];
}

// ---------------- LayerNorm -> bf16 ----------------
__global__ __launch_bounds__(256) void ln_to_bf16(const float* __restrict__ src, const float* __restrict__ gamma,
    u16* __restrict__ dst, int stable){
  __shared__ float red[4];
  int row = blockIdx.x;
  const float* s = src + (size_t)row*DIM_;
  int tid = threadIdx.x, wv = tid>>6, ln = tid&63;
  float v0 = s[tid], v1 = s[tid+256], v2 = s[tid+512];
  if (stable){
    float m = wmax(fmaxf(fmaxf(v0,v1),v2));
    if (ln==0) red[wv]=m;
    __syncthreads();
    m = fmaxf(fmaxf(red[0],red[1]),fmaxf(red[2],red[3]));
    __syncthreads();
    float inv = 1.0f/m; v0*=inv; v1*=inv; v2*=inv;
  }
  float sum = wsum(v0+v1+v2);
  if (ln==0) red[wv]=sum;
  __syncthreads();
  sum = red[0]+red[1]+red[2]+red[3];
  __syncthreads();
  float mean = sum * (1.0f/DIM_);
  float d0=v0-mean, d1=v1-mean, d2=v2-mean;
  float sq = wsum(d0*d0+d1*d1+d2*d2);
  if (ln==0) red[wv]=sq;
  __syncthreads();
  sq = red[0]+red[1]+red[2]+red[3];
  float inv = rsqrtf(sq*(1.0f/DIM_) + 1e-5f);
  u16* d = dst + (size_t)row*DIM_;
  d[tid]     = f2bf(d0*inv*gamma[tid]);
  d[tid+256] = f2bf(d1*inv*gamma[tid+256]);
  d[tid+512] = f2bf(d2*inv*gamma[tid+512]);
}

// ---------------- x += LN(src) (f32) ----------------
__global__ __launch_bounds__(256) void ln_resid(const float* __restrict__ src, const float* __restrict__ gamma,
    float* __restrict__ x){
  __shared__ float red[4];
  int row = blockIdx.x;
  const float* s = src + (size_t)row*DIM_;
  int tid = threadIdx.x, wv = tid>>6, ln = tid&63;
  float v0 = s[tid], v1 = s[tid+256], v2 = s[tid+512];
  float sum = wsum(v0+v1+v2);
  if (ln==0) red[wv]=sum;
  __syncthreads();
  sum = red[0]+red[1]+red[2]+red[3];
  __syncthreads();
  float mean = sum * (1.0f/DIM_);
  float d0=v0-mean, d1=v1-mean, d2=v2-mean;
  float sq = wsum(d0*d0+d1*d1+d2*d2);
  if (ln==0) red[wv]=sq;
  __syncthreads();
  sq = red[0]+red[1]+red[2]+red[3];
  float inv = rsqrtf(sq*(1.0f/DIM_) + 1e-5f);
  float* xr = x + (size_t)row*DIM_;
  xr[tid]     += d0*inv*gamma[tid];
  xr[tid+256] += d1*inv*gamma[tid+256];
  xr[tid+512] += d2*inv*gamma[tid+512];
}

// ---------------- bf16 MFMA GEMM: A[M][K] bf16, Bt[N][K] bf16 -> C[M][N] ----------------
// mode 0: f32 -> Cf ; mode 1: bf16 -> Ch ; mode 2: Xres += acc
// GATED=1: second B tile at rows FFI_+col, out = a*silu(g) bf16 -> Ch
template<int GATED>
__global__ __launch_bounds__(256) void gemm_bf16(const u16* __restrict__ A, const u16* __restrict__ Bt,
    int M, int N, int K, float* __restrict__ Cf, u16* __restrict__ Ch,
    float* __restrict__ Xres, int mode, int gather){
  __shared__ u16 Al[128*32];
  __shared__ u16 Bl[128*32];
  __shared__ u16 Gl[GATED ? 128*32 : 4];
  int tid = threadIdx.x;
  int lane = tid & 63, wave = tid >> 6;
  int g = lane >> 4, c = lane & 15;
  int row0 = blockIdx.y * 128, col0 = blockIdx.x * 128;
  int wr = (wave >> 1) * 64, wc = (wave & 1) * 64;

  f32x4 acc[4][4];
  f32x4 accg[4][4];
#pragma unroll
  for (int i=0;i<4;++i)
#pragma unroll
    for (int j=0;j<4;++j){ acc[i][j] = (f32x4){0,0,0,0}; accg[i][j] = (f32x4){0,0,0,0}; }

  auto stageT = [&](const u16* __restrict__ src, int r0, int rmax, int ld, int k0, u16* lds, bool remap){
#pragma unroll
    for (int u=0; u<2; ++u){
      int idx = u*256 + tid;          // 0..511
      int r = idx >> 2, c8 = (idx & 3) << 3;
      int rr = r0 + r; if (rr >= rmax) rr = rmax-1;
      if (remap){ int bb = rr / NT_, t = rr - bb*NT_; rr = bb*NTOK_ + 258 + t; }
      uint4 v = *(const uint4*)(src + (size_t)rr*ld + k0 + c8);
      *(uint4*)(lds + idx*8) = v;
    }
  };

  for (int k0 = 0; k0 < K; k0 += 32){
    stageT(A, row0, M, K, k0, Al, gather != 0);
    stageT(Bt, col0, GATED ? FFI_ : N, K, k0, Bl, false);
    if constexpr (GATED) stageT(Bt, FFI_ + col0, 2*FFI_, K, k0, Gl, false);
    __syncthreads();
    short8 af[4], bf[4], gf[4];
#pragma unroll
    for (int mi=0; mi<4; ++mi)
      af[mi] = *(const short8*)(Al + (wr + mi*16 + c)*32 + g*8);
#pragma unroll
    for (int ni=0; ni<4; ++ni)
      bf[ni] = *(const short8*)(Bl + (wc + ni*16 + c)*32 + g*8);
    if constexpr (GATED){
#pragma unroll
      for (int ni=0; ni<4; ++ni)
        gf[ni] = *(const short8*)(Gl + (wc + ni*16 + c)*32 + g*8);
    }
#pragma unroll
    for (int mi=0; mi<4; ++mi)
#pragma unroll
      for (int ni=0; ni<4; ++ni){
        acc[mi][ni] = __builtin_amdgcn_mfma_f32_16x16x32_bf16(af[mi], bf[ni], acc[mi][ni], 0,0,0);
        if constexpr (GATED)
          accg[mi][ni] = __builtin_amdgcn_mfma_f32_16x16x32_bf16(af[mi], gf[ni], accg[mi][ni], 0,0,0);
      }
    __syncthreads();
  }

#pragma unroll
  for (int mi=0; mi<4; ++mi){
#pragma unroll
    for (int t=0; t<4; ++t){
      int r = row0 + wr + mi*16 + g*4 + t;
      if (r < M){
#pragma unroll
        for (int ni=0; ni<4; ++ni){
          int cc = col0 + wc + ni*16 + c;
          float v = acc[mi][ni][t];
          if constexpr (GATED){
            float gv = accg[mi][ni][t];
            Ch[(size_t)r*N + cc] = f2bf(v * (gv / (1.0f + __expf(-gv))));
          } else {
            if (mode == 0)      Cf[(size_t)r*N + cc] = v;
            else if (mode == 1) Ch[(size_t)r*N + cc] = f2bf(v);
            else                Xres[(size_t)r*N + cc] += v;
          }
        }
      }
    }
  }
}

// ---------------- RoPE + l2norm + scale on q (bf16 in-place) ----------------
__global__ __launch_bounds__(256) void qprep(u16* __restrict__ q){
  int vec = blockIdx.x*4 + (threadIdx.x>>6);
  int lane = threadIdx.x & 63;
  if (vec >= NROW_*HEADS_) return;
  int n = (vec/HEADS_) % NTOK_;
  u16* p = q + (size_t)vec*DH_ + lane;
  float v = bf2f(*p);
  float t1 = __shfl(v, lane & 62);
  float t2 = __shfl(v, lane | 1);
  float out = v;
  if (lane < 32){
    int ii = lane >> 1;
    float invf = __expf(-logf(10000.0f) * (float)ii / 16.0f);
    float fr = (float)n * invf;
    float cs = cosf(fr), sn = sinf(fr);
    out = (lane & 1) ? (t1*sn + t2*cs) : (t1*cs - t2*sn);
  }
  float sq = wsum(out*out);
  float nrm = fmaxf(sqrtf(sq), 1e-12f);
  *p = f2bf(out * (4.0f/nrm));
}

// ---------------- build k/v (bf16) with null at j=0; RoPE+l2norm on k ----------------
__global__ __launch_bounds__(256) void kvprep(const u16* __restrict__ kv, const float* __restrict__ nullkv,
    u16* __restrict__ kh, u16* __restrict__ vh){
  int idx = blockIdx.x*4 + (threadIdx.x>>6);
  if (idx >= B_*NKEY_) return;
  int b = idx / NKEY_, j = idx % NKEY_;
  int lane = threadIdx.x & 63;
  float kl, vl;
  if (j == 0){ kl = nullkv[lane]; vl = nullkv[DH_+lane]; }
  else {
    const u16* row = kv + (size_t)(b*NTOK_ + (j-1))*(2*DH_);
    kl = bf2f(row[lane]); vl = bf2f(row[DH_+lane]);
  }
  float t1 = __shfl(kl, lane & 62);
  float t2 = __shfl(kl, lane | 1);
  if (j > 0 && lane < 32){
    int ii = lane >> 1;
    float invf = __expf(-logf(10000.0f) * (float)ii / 16.0f);
    float fr = (float)(j-1) * invf;
    float cs = cosf(fr), sn = sinf(fr);
    kl = (lane & 1) ? (t1*sn + t2*cs) : (t1*cs - t2*sn);
  }
  float sq = wsum(kl*kl);
  float nrm = fmaxf(sqrtf(sq), 1e-12f);
  kh[((size_t)b*NKEY_+j)*DH_+lane] = f2bf(kl*(4.0f/nrm));
  vh[((size_t)b*NKEY_+j)*DH_+lane] = f2bf(vl);
}

// ---------------- fused flash attention (MFMA), block = (qtile, h, b) ----------------
__global__ __launch_bounds__(256) void attn_mfma(const u16* __restrict__ qh, const u16* __restrict__ kh,
    const u16* __restrict__ vh, const float* __restrict__ bias_d, u16* __restrict__ oh){
  __shared__ u16 q_lds[64*72];
  __shared__ u16 k_lds[64*72];
  __shared__ u16 vt_lds[64*72];
  __shared__ float bias_lds[NTOK_];
  __shared__ u16 p_lds[4][16*72];
  int qt = blockIdx.x, h = blockIdx.y, b = blockIdx.z;
  int tid = threadIdx.x, wave = tid>>6, lane = tid&63;
  int g = lane>>4, c = lane&15;

  {
    int i2 = tid >> 2;
    int d0 = (tid & 3) << 4;
    int gi = qt*64 + i2; if (gi >= NTOK_) gi = NTOK_-1;
    const u16* src = qh + (((size_t)(b*NTOK_+gi))*HEADS_ + h)*DH_ + d0;
    uint4 v0 = *(const uint4*)src;
    uint4 v1 = *(const uint4*)(src+8);
    *(uint4*)&q_lds[i2*72 + d0] = v0;
    *(uint4*)&q_lds[i2*72 + d0 + 8] = v1;
  }
  for (int u=tid; u<NTOK_; u+=256) bias_lds[u] = bias_d[h*NTOK_ + u];
  __syncthreads();

  short8 aq[2];
  int rbase = wave*16;
#pragma unroll
  for (int dk=0; dk<2; ++dk)
    aq[dk] = *(const short8*)&q_lds[(rbase + c)*72 + dk*32 + g*8];

  f32x4 o[4];
  float m[4], lsum[4];
#pragma unroll
  for (int dg=0; dg<4; ++dg) o[dg] = (f32x4){0,0,0,0};
#pragma unroll
  for (int t=0; t<4; ++t){ m[t] = -3e38f; lsum[t] = 0.f; }
  int ibase = qt*64 + wave*16;

  for (int jt=0; jt<9; ++jt){
    __syncthreads();
    {
      int j2 = tid >> 2, d0 = (tid&3) << 4;
      int gj = jt*64 + j2; if (gj >= NKEY_) gj = NKEY_-1;
      const u16* ks = kh + ((size_t)b*NKEY_ + gj)*DH_ + d0;
      uint4 k0v = *(const uint4*)ks; uint4 k1v = *(const uint4*)(ks+8);
      *(uint4*)&k_lds[j2*72 + d0] = k0v;
      *(uint4*)&k_lds[j2*72 + d0 + 8] = k1v;
      const u16* vs = vh + ((size_t)b*NKEY_ + gj)*DH_ + d0;
      u16 tmp[16];
      *(uint4*)&tmp[0] = *(const uint4*)vs;
      *(uint4*)&tmp[8] = *(const uint4*)(vs+8);
#pragma unroll
      for (int e=0; e<16; ++e) vt_lds[(d0+e)*72 + j2] = tmp[e];
    }
    __syncthreads();

    f32x4 s[4];
#pragma unroll
    for (int jc=0; jc<4; ++jc){
      f32x4 z = (f32x4){0,0,0,0};
#pragma unroll
      for (int dk=0; dk<2; ++dk){
        short8 bk = *(const short8*)&k_lds[(jc*16 + c)*72 + dk*32 + g*8];
        z = __builtin_amdgcn_mfma_f32_16x16x32_bf16(aq[dk], bk, z, 0,0,0);
      }
      s[jc] = z;
    }

    float rowmax[4];
#pragma unroll
    for (int t=0; t<4; ++t) rowmax[t] = -3e38f;
#pragma unroll
    for (int jc=0; jc<4; ++jc){
      int j = jt*64 + jc*16 + c;
#pragma unroll
      for (int t=0; t<4; ++t){
        int i = ibase + g*4 + t;
        int d = i - j; if (d < 0) d = 0; if (d > NTOK_-1) d = NTOK_-1;
        float sv = s[jc][t] + bias_lds[d];
        if (j > i+1) sv = -1e30f;
        s[jc][t] = sv;
        rowmax[t] = fmaxf(rowmax[t], sv);
      }
    }
#pragma unroll
    for (int t=0; t<4; ++t){
      float v = rowmax[t];
      v = fmaxf(v, __shfl_xor(v,1));
      v = fmaxf(v, __shfl_xor(v,2));
      v = fmaxf(v, __shfl_xor(v,4));
      v = fmaxf(v, __shfl_xor(v,8));
      rowmax[t] = v;
    }
    float scale_[4], rs[4];
#pragma unroll
    for (int t=0;t<4;++t){
      float mn = fmaxf(m[t], rowmax[t]);
      scale_[t] = __expf(m[t] - mn);
      m[t] = mn;
      rs[t] = 0.f;
    }
    u16* pl = &p_lds[wave][0];
#pragma unroll
    for (int jc=0; jc<4; ++jc){
#pragma unroll
      for (int t=0; t<4; ++t){
        float p = __expf(s[jc][t] - m[t]);
        rs[t] += p;
        pl[(g*4 + t)*72 + jc*16 + c] = f2bf(p);
      }
    }
#pragma unroll
    for (int t=0;t<4;++t){
      float v = rs[t];
      v += __shfl_xor(v,1); v += __shfl_xor(v,2); v += __shfl_xor(v,4); v += __shfl_xor(v,8);
      lsum[t] = lsum[t]*scale_[t] + v;
    }
#pragma unroll
    for (int dg=0; dg<4; ++dg)
#pragma unroll
      for (int t=0;t<4;++t) o[dg][t] *= scale_[t];
#pragma unroll
    for (int ks=0; ks<2; ++ks){
      short8 ap = *(const short8*)&pl[c*72 + ks*32 + g*8];
#pragma unroll
      for (int dg=0; dg<4; ++dg){
        short8 bv = *(const short8*)&vt_lds[(dg*16 + c)*72 + ks*32 + g*8];
        o[dg] = __builtin_amdgcn_mfma_f32_16x16x32_bf16(ap, bv, o[dg], 0,0,0);
      }
    }
  }

#pragma unroll
  for (int t=0;t<4;++t){
    int i = ibase + g*4 + t;
    if (i < NTOK_){
      float inv = 1.0f / lsum[t];
#pragma unroll
      for (int dg=0; dg<4; ++dg)
        oh[(((size_t)(b*NTOK_+i))*HEADS_ + h)*DH_ + dg*16 + c] = f2bf(o[dg][t] * inv);
    }
  }
}

extern "C" void kernel_launch(void* const* d_in, const int* in_sizes, int n_in,
                              void* d_out, int out_size, void* d_ws, size_t ws_size,
                              hipStream_t stream) {
  const float* image = (const float*)d_in[0];
  const float* brain = (const float*)d_in[1];
  const int*   tsteps= (const int*)  d_in[2];
  const float* lq    = (const float*)d_in[3];
  const float* t_w1  = (const float*)d_in[4];
  const float* t_b1  = (const float*)d_in[5];
  const float* t_w2  = (const float*)d_in[6];
  const float* t_b2  = (const float*)d_in[7];
  const float* t_w3  = (const float*)d_in[8];
  const float* t_b3  = (const float*)d_in[9];
  const float* relpos= (const float*)d_in[10];
  const float* anorm = (const float*)d_in[11];
  const float* Wq    = (const float*)d_in[12];
  const float* Wkv   = (const float*)d_in[13];
  const float* nkv   = (const float*)d_in[14];
  const float* Wo    = (const float*)d_in[15];
  const float* aoutg = (const float*)d_in[16];
  const float* fng   = (const float*)d_in[17];
  const float* Win   = (const float*)d_in[18];
  const float* Wout  = (const float*)d_in[19];
  const float* fing  = (const float*)d_in[20];
  const float* Wproj = (const float*)d_in[21];
  float* out = (float*)d_out;

  float* p = (float*)d_ws;
  auto alloc = [&](size_t nfl){ float* r = p; p += nfl; return r; };
  const size_t SZ_X = (size_t)NROW_*DIM_;
  float* x     = alloc(SZ_X);
  float* ubu   = alloc((size_t)NROW_*FFI_/2);      // union: tb f32 | ub bf16
  u16*   xnh   = (u16*)alloc(SZ_X/2);
  u16*   qh    = (u16*)alloc(SZ_X/2);
  u16*   kvb   = (u16*)alloc((size_t)NROW_*128/2);
  u16*   kh    = (u16*)alloc((size_t)B_*NKEY_*DH_/2);
  u16*   vh    = (u16*)alloc((size_t)B_*NKEY_*DH_/2);
  u16*   oh    = (u16*)alloc(SZ_X/2);
  u16*   WqT   = (u16*)alloc((size_t)DEPTH_*DIM_*DIM_/2);
  u16*   WkvT  = (u16*)alloc((size_t)DEPTH_*DIM_*128/2);
  u16*   WoT   = (u16*)alloc((size_t)DEPTH_*DIM_*DIM_/2);
  u16*   WinT  = (u16*)alloc((size_t)DEPTH_*DIM_*2*FFI_/2);
  u16*   WoutT = (u16*)alloc((size_t)DEPTH_*FFI_*DIM_/2);
  u16*   WprojT= (u16*)alloc((size_t)DIM_*DIM_/2);
  float* pe    = alloc(8*768);
  float* h1    = alloc(8*1536);
  float* h2    = alloc(8*1536);
  float* temb  = alloc(8*768);
  float* biasd = alloc(HEADS_*NTOK_ + 4);
  float* tb    = ubu;
  u16*   ub    = (u16*)ubu;

  // weight transposes (f32 -> bf16 [N][K])
  transpose_bf16<<<dim3(DIM_/32, DIM_/32, DEPTH_),256,0,stream>>>(Wq, WqT, DIM_, DIM_);
  transpose_bf16<<<dim3(128/32,  DIM_/32, DEPTH_),256,0,stream>>>(Wkv, WkvT, DIM_, 128);
  transpose_bf16<<<dim3(DIM_/32, DIM_/32, DEPTH_),256,0,stream>>>(Wo, WoT, DIM_, DIM_);
  transpose_bf16<<<dim3(2*FFI_/32, DIM_/32, DEPTH_),256,0,stream>>>(Win, WinT, DIM_, 2*FFI_);
  transpose_bf16<<<dim3(DIM_/32, FFI_/32, DEPTH_),256,0,stream>>>(Wout, WoutT, FFI_, DIM_);
  transpose_bf16<<<dim3(DIM_/32, DIM_/32, 1),256,0,stream>>>(Wproj, WprojT, DIM_, DIM_);

  // time embedding
  pe_kernel<<<B_,256,0,stream>>>(tsteps, pe);
  fc_kernel<<<1536/64,256,8*768*4,stream>>>(pe, t_w1, t_b1, h1, 768, 1536, 1);
  fc_kernel<<<1536/64,256,8*1536*4,stream>>>(h1, t_w2, t_b2, h2, 1536, 1536, 1);
  fc_kernel<<<768/64,256,8*1536*4,stream>>>(h2, t_w3, t_b3, temb, 1536, 768, 0);

  build_tokens<<<NROW_,256,0,stream>>>(brain, image, lq, temb, x);
  bias_delta<<<(NTOK_+255)/256,256,0,stream>>>(relpos, biasd);

  for (int l=0; l<DEPTH_; ++l){
    ln_to_bf16<<<NROW_,256,0,stream>>>(x, anorm + (size_t)l*DIM_, xnh, 0);
    gemm_bf16<0><<<dim3(6,33),256,0,stream>>>(xnh, WqT + (size_t)l*DIM_*DIM_, NROW_, DIM_, DIM_,
                                              nullptr, qh, nullptr, 1, 0);
    gemm_bf16<0><<<dim3(1,33),256,0,stream>>>(xnh, WkvT + (size_t)l*DIM_*128, NROW_, 128, DIM_,
                                              nullptr, kvb, nullptr, 1, 0);
    qprep<<<NROW_*HEADS_/4,256,0,stream>>>(qh);
    kvprep<<<B_*NKEY_/4,256,0,stream>>>(kvb, nkv + (size_t)l*2*DH_, kh, vh);
    attn_mfma<<<dim3(9,HEADS_,B_),256,0,stream>>>(qh, kh, vh, biasd, oh);
    gemm_bf16<0><<<dim3(6,33),256,0,stream>>>(oh, WoT + (size_t)l*DIM_*DIM_, NROW_, DIM_, DIM_,
                                              tb, nullptr, nullptr, 0, 0);
    ln_resid<<<NROW_,256,0,stream>>>(tb, aoutg + (size_t)l*DIM_, x);
    ln_to_bf16<<<NROW_,256,0,stream>>>(x, fng + (size_t)l*DIM_, xnh, 0);
    gemm_bf16<1><<<dim3(24,33),256,0,stream>>>(xnh, WinT + (size_t)l*DIM_*2*FFI_, NROW_, FFI_, DIM_,
                                               nullptr, ub, nullptr, 3, 0);
    gemm_bf16<0><<<dim3(6,33),256,0,stream>>>(ub, WoutT + (size_t)l*FFI_*DIM_, NROW_, DIM_, FFI_,
                                              nullptr, nullptr, x, 2, 0);
  }

  ln_to_bf16<<<NROW_,256,0,stream>>>(x, fing, xnh, 1);
  gemm_bf16<0><<<dim3(6,17),256,0,stream>>>(xnh, WprojT, B_*NT_, DIM_, DIM_,
                                            out, nullptr, nullptr, 0, 1);
}

// Round 4
// 2612.651 us; speedup vs baseline: 4.1574x; 1.1664x over previous
//
#include <hip/hip_runtime.h>
#include <cfloat>
#include <cmath>

#define B_      8
#define NT_     257
#define DIM_    768
#define HEADS_  12
#define DH_     64
#define DEPTH_  6
#define NTOK_   515        // brain(257) + time(1) + image(257)
#define NKEY_   516        // + null kv
#define NROW_   (B_*NTOK_) // 4120
#define FFI_    3072

typedef unsigned short u16;
typedef __attribute__((ext_vector_type(8))) short short8;
typedef __attribute__((ext_vector_type(4))) float f32x4;

__device__ __forceinline__ u16 f2bf(float f){
  union { float f; unsigned u; } v; v.f = f;
  unsigned r = v.u + 0x7fffu + ((v.u >> 16) & 1u);
  return (u16)(r >> 16);
}
__device__ __forceinline__ float bf2f(u16 h){
  union { unsigned u; float f; } v; v.u = ((unsigned)h) << 16;
  return v.f;
}
__device__ __forceinline__ float wsum(float v){
#pragma unroll
  for (int o=32;o;o>>=1) v += __shfl_xor(v,o);
  return v;
}
__device__ __forceinline__ float wmax(float v){
#pragma unroll
  for (int o=32;o;o>>=1) v = fmaxf(v,__shfl_xor(v,o));
  return v;
}
// async global->LDS, 16B per lane; lp must be wave-uniform chunk base
__device__ __forceinline__ void gload16(const u16* gp, u16* lp){
  __builtin_amdgcn_global_load_lds(
      (const __attribute__((address_space(1))) unsigned int*)gp,
      (__attribute__((address_space(3))) unsigned int*)lp, 16, 0, 0);
}

// ---------------- transpose f32 [K][N] -> bf16 [N][K], batched over z ----------------
__global__ __launch_bounds__(256) void transpose_bf16(const float* __restrict__ src, u16* __restrict__ dst,
    int K, int N){
  __shared__ float tile[32][33];
  size_t zoff = (size_t)blockIdx.z * K * N;
  src += zoff; dst += zoff;
  int c0 = blockIdx.x*32, r0 = blockIdx.y*32;
  int tx = threadIdx.x & 31, ty = threadIdx.x >> 5;
#pragma unroll
  for (int u=0; u<4; ++u){
    int r = ty*4 + u;
    tile[r][tx] = src[(size_t)(r0 + r)*N + c0 + tx];
  }
  __syncthreads();
#pragma unroll
  for (int u=0; u<4; ++u){
    int r = ty*4 + u;
    dst[(size_t)(c0 + r)*K + r0 + tx] = f2bf(tile[tx][r]);
  }
}

// ---------------- time-embedding ----------------
__global__ __launch_bounds__(256) void pe_kernel(const int* __restrict__ ts, float* __restrict__ pe){
  int b = blockIdx.x;
  float t = (float)ts[b];
  const float cc = -logf(10000.0f)/383.0f;
  for (int i=threadIdx.x; i<768; i+=256){
    int k = (i<384)? i : i-384;
    float f = __expf((float)k*cc);
    pe[b*768+i] = (i<384)? sinf(t*f) : cosf(t*f);
  }
}
__global__ __launch_bounds__(256) void fc_init(const float* __restrict__ bias, float* __restrict__ out, int N){
  int i = blockIdx.x*256 + threadIdx.x;
  if (i < 8*N) out[i] = bias[i % N];
}
// split-K fc: out[8][N] += in(8xK slice) @ W ; silu applied to INPUT if act_in
__global__ __launch_bounds__(256) void fc_split(const float* __restrict__ in, const float* __restrict__ W,
    float* __restrict__ out, int K, int N, int act_in){
  __shared__ float in_lds[8][128];
  __shared__ float red[4][8][64];
  int kg = threadIdx.x >> 6;
  int c  = threadIdx.x & 63;
  int col = blockIdx.x*64 + c;
  int k0 = blockIdx.y*128;
  for (int idx = threadIdx.x; idx < 8*128; idx += 256){
    int r = idx >> 7, k = idx & 127;
    float v = in[(size_t)r*K + k0 + k];
    if (act_in) v = v/(1.0f+__expf(-v));
    in_lds[r][k] = v;
  }
  __syncthreads();
  float acc[8] = {0,0,0,0,0,0,0,0};
  const float* wp = W + (size_t)(k0 + kg*32)*N + col;
#pragma unroll 4
  for (int kk=0; kk<32; ++kk){
    float w = wp[(size_t)kk*N];
#pragma unroll
    for (int r=0;r<8;++r) acc[r] += in_lds[r][kg*32+kk]*w;
  }
#pragma unroll
  for (int r=0;r<8;++r) red[kg][r][c] = acc[r];
  __syncthreads();
  for (int p2 = threadIdx.x; p2 < 512; p2 += 256){
    int r = p2 >> 6, cc = p2 & 63;
    float s = red[0][r][cc]+red[1][r][cc]+red[2][r][cc]+red[3][r][cc];
    atomicAdd(out + (size_t)r*N + blockIdx.x*64 + cc, s);
  }
}

// ---------------- build token sequence (f32) ----------------
__global__ __launch_bounds__(256) void build_tokens(const float* __restrict__ brain,
    const float* __restrict__ image, const float* __restrict__ lq,
    const float* __restrict__ temb, float* __restrict__ x){
  int row = blockIdx.x;
  int b = row / NTOK_, t = row % NTOK_;
  int tid = threadIdx.x;
#pragma unroll
  for (int u=0;u<3;++u){
    int d = tid + u*256;
    float val;
    if (t < 257)      val = brain[((size_t)(b*257+t))*DIM_ + d];
    else if (t == 257) val = temb[(size_t)b*DIM_ + d];
    else               val = image[((size_t)(b*257 + (t-258)))*DIM_ + d] + lq[((size_t)(t-258))*DIM_ + d];
    x[(size_t)row*DIM_ + d] = val;
  }
}

// ---------------- rel-pos bias by delta ----------------
__global__ __launch_bounds__(256) void bias_delta(const float* __restrict__ emb, float* __restrict__ bias_d){
  int d = blockIdx.x*256 + threadIdx.x;
  if (d >= NTOK_) return;
  int bucket;
  if (d < 16) bucket = d;
  else {
    int lg = 16 + (int)(logf((float)d * (1.0f/16.0f)) * (16.0f/logf(8.0f)));
    bucket = lg < 31 ? lg : 31;
  }
  for (int h=0; h<HEADS_; ++h) bias_d[h*NTOK_ + d] = emb[bucket*HEADS_ + h];
}

// ---------------- LayerNorm -> bf16 ----------------
__global__ __launch_bounds__(256) void ln_to_bf16(const float* __restrict__ src, const float* __restrict__ gamma,
    u16* __restrict__ dst, int stable){
  __shared__ float red[4];
  int row = blockIdx.x;
  const float* s = src + (size_t)row*DIM_;
  int tid = threadIdx.x, wv = tid>>6, ln = tid&63;
  float v0 = s[tid], v1 = s[tid+256], v2 = s[tid+512];
  if (stable){
    float m = wmax(fmaxf(fmaxf(v0,v1),v2));
    if (ln==0) red[wv]=m;
    __syncthreads();
    m = fmaxf(fmaxf(red[0],red[1]),fmaxf(red[2],red[3]));
    __syncthreads();
    float inv = 1.0f/m; v0*=inv; v1*=inv; v2*=inv;
  }
  float sum = wsum(v0+v1+v2);
  if (ln==0) red[wv]=sum;
  __syncthreads();
  sum = red[0]+red[1]+red[2]+red[3];
  __syncthreads();
  float mean = sum * (1.0f/DIM_);
  float d0=v0-mean, d1=v1-mean, d2=v2-mean;
  float sq = wsum(d0*d0+d1*d1+d2*d2);
  if (ln==0) red[wv]=sq;
  __syncthreads();
  sq = red[0]+red[1]+red[2]+red[3];
  float inv = rsqrtf(sq*(1.0f/DIM_) + 1e-5f);
  u16* d = dst + (size_t)row*DIM_;
  d[tid]     = f2bf(d0*inv*gamma[tid]);
  d[tid+256] = f2bf(d1*inv*gamma[tid+256]);
  d[tid+512] = f2bf(d2*inv*gamma[tid+512]);
}

// ---------------- x += LN(src) (f32) ----------------
__global__ __launch_bounds__(256) void ln_resid(const float* __restrict__ src, const float* __restrict__ gamma,
    float* __restrict__ x){
  __shared__ float red[4];
  int row = blockIdx.x;
  const float* s = src + (size_t)row*DIM_;
  int tid = threadIdx.x, wv = tid>>6, ln = tid&63;
  float v0 = s[tid], v1 = s[tid+256], v2 = s[tid+512];
  float sum = wsum(v0+v1+v2);
  if (ln==0) red[wv]=sum;
  __syncthreads();
  sum = red[0]+red[1]+red[2]+red[3];
  __syncthreads();
  float mean = sum * (1.0f/DIM_);
  float d0=v0-mean, d1=v1-mean, d2=v2-mean;
  float sq = wsum(d0*d0+d1*d1+d2*d2);
  if (ln==0) red[wv]=sq;
  __syncthreads();
  sq = red[0]+red[1]+red[2]+red[3];
  float inv = rsqrtf(sq*(1.0f/DIM_) + 1e-5f);
  float* xr = x + (size_t)row*DIM_;
  xr[tid]     += d0*inv*gamma[tid];
  xr[tid+256] += d1*inv*gamma[tid+256];
  xr[tid+512] += d2*inv*gamma[tid+512];
}

// ---------------- bf16 MFMA GEMM: A[M][K] bf16, Bt[N][K] bf16 -> C[M][N] ----------------
// LDS tiles [128][32] u16 linear (global_load_lds dest); XOR swizzle: slot s -> s^((row>>1)&3)
// applied on SOURCE address at stage time and on READ address (involution).
template<int GATED>
__global__ __launch_bounds__(256) void gemm_bf16(const u16* __restrict__ A, const u16* __restrict__ Bt,
    int M, int N, int K, float* __restrict__ Cf, u16* __restrict__ Ch,
    float* __restrict__ Xres, int mode, int gather){
  __shared__ u16 Al[128*32];
  __shared__ u16 Bl[128*32];
  __shared__ u16 Gl[GATED ? 128*32 : 4];
  int tid = threadIdx.x;
  int lane = tid & 63, wave = tid >> 6;
  int g = lane >> 4, c = lane & 15;
  int row0 = blockIdx.y * 128, col0 = blockIdx.x * 128;
  int wr = (wave >> 1) * 64, wc = (wave & 1) * 64;

  f32x4 acc[4][4];
  f32x4 accg[4][4];
#pragma unroll
  for (int i=0;i<4;++i)
#pragma unroll
    for (int j=0;j<4;++j){ acc[i][j] = (f32x4){0,0,0,0}; accg[i][j] = (f32x4){0,0,0,0}; }

  auto stage = [&](const u16* __restrict__ src, int r0, int rmax, int ld, int k0, u16* lds, bool remap){
#pragma unroll
    for (int u=0; u<2; ++u){
      int idx = u*256 + tid;          // 0..511 (16B units)
      int r = idx >> 2;               // tile row 0..127
      int s = idx & 3;                // 16B slot
      int ss = s ^ ((r>>1)&3);        // inverse swizzle on source
      int rr = r0 + r; if (rr >= rmax) rr = rmax-1;
      if (remap){ int bb = rr / NT_, t = rr - bb*NT_; rr = bb*NTOK_ + 258 + t; }
      gload16(src + (size_t)rr*ld + k0 + ss*8, lds + (size_t)(u*256 + wave*64)*8);
    }
  };

  for (int k0 = 0; k0 < K; k0 += 32){
    stage(A, row0, M, K, k0, Al, gather != 0);
    stage(Bt, col0, GATED ? FFI_ : N, K, k0, Bl, false);
    if constexpr (GATED) stage(Bt, FFI_ + col0, 2*FFI_, K, k0, Gl, false);
    __syncthreads();
    short8 af[4], bf[4], gf[4];
    int sw = (g ^ ((c>>1)&3)) * 8;    // swizzled slot offset (row = 16a+c -> sigma=(c>>1)&3)
#pragma unroll
    for (int mi=0; mi<4; ++mi)
      af[mi] = *(const short8*)(Al + (wr + mi*16 + c)*32 + sw);
#pragma unroll
    for (int ni=0; ni<4; ++ni)
      bf[ni] = *(const short8*)(Bl + (wc + ni*16 + c)*32 + sw);
    if constexpr (GATED){
#pragma unroll
      for (int ni=0; ni<4; ++ni)
        gf[ni] = *(const short8*)(Gl + (wc + ni*16 + c)*32 + sw);
    }
#pragma unroll
    for (int mi=0; mi<4; ++mi)
#pragma unroll
      for (int ni=0; ni<4; ++ni){
        acc[mi][ni] = __builtin_amdgcn_mfma_f32_16x16x32_bf16(af[mi], bf[ni], acc[mi][ni], 0,0,0);
        if constexpr (GATED)
          accg[mi][ni] = __builtin_amdgcn_mfma_f32_16x16x32_bf16(af[mi], gf[ni], accg[mi][ni], 0,0,0);
      }
    __syncthreads();
  }

#pragma unroll
  for (int mi=0; mi<4; ++mi){
#pragma unroll
    for (int t=0; t<4; ++t){
      int r = row0 + wr + mi*16 + g*4 + t;
      if (r < M){
#pragma unroll
        for (int ni=0; ni<4; ++ni){
          int cc = col0 + wc + ni*16 + c;
          float v = acc[mi][ni][t];
          if constexpr (GATED){
            float gv = accg[mi][ni][t];
            Ch[(size_t)r*N + cc] = f2bf(v * (gv / (1.0f + __expf(-gv))));
          } else {
            if (mode == 0)      Cf[(size_t)r*N + cc] = v;
            else if (mode == 1) Ch[(size_t)r*N + cc] = f2bf(v);
            else                Xres[(size_t)r*N + cc] += v;
          }
        }
      }
    }
  }
}

// ---------------- RoPE + l2norm + scale on q (bf16 in-place) ----------------
__global__ __launch_bounds__(256) void qprep(u16* __restrict__ q){
  int vec = blockIdx.x*4 + (threadIdx.x>>6);
  int lane = threadIdx.x & 63;
  if (vec >= NROW_*HEADS_) return;
  int n = (vec/HEADS_) % NTOK_;
  u16* p = q + (size_t)vec*DH_ + lane;
  float v = bf2f(*p);
  float t1 = __shfl(v, lane & 62);
  float t2 = __shfl(v, lane | 1);
  float out = v;
  if (lane < 32){
    int ii = lane >> 1;
    float invf = __expf(-logf(10000.0f) * (float)ii / 16.0f);
    float fr = (float)n * invf;
    float cs = cosf(fr), sn = sinf(fr);
    out = (lane & 1) ? (t1*sn + t2*cs) : (t1*cs - t2*sn);
  }
  float sq = wsum(out*out);
  float nrm = fmaxf(sqrtf(sq), 1e-12f);
  *p = f2bf(out * (4.0f/nrm));
}

// ---------------- build k/v (bf16) with null at j=0; RoPE+l2norm on k ----------------
__global__ __launch_bounds__(256) void kvprep(const u16* __restrict__ kv, const float* __restrict__ nullkv,
    u16* __restrict__ kh, u16* __restrict__ vh){
  int idx = blockIdx.x*4 + (threadIdx.x>>6);
  if (idx >= B_*NKEY_) return;
  int b = idx / NKEY_, j = idx % NKEY_;
  int lane = threadIdx.x & 63;
  float kl, vl;
  if (j == 0){ kl = nullkv[lane]; vl = nullkv[DH_+lane]; }
  else {
    const u16* row = kv + (size_t)(b*NTOK_ + (j-1))*(2*DH_);
    kl = bf2f(row[lane]); vl = bf2f(row[DH_+lane]);
  }
  float t1 = __shfl(kl, lane & 62);
  float t2 = __shfl(kl, lane | 1);
  if (j > 0 && lane < 32){
    int ii = lane >> 1;
    float invf = __expf(-logf(10000.0f) * (float)ii / 16.0f);
    float fr = (float)(j-1) * invf;
    float cs = cosf(fr), sn = sinf(fr);
    kl = (lane & 1) ? (t1*sn + t2*cs) : (t1*cs - t2*sn);
  }
  float sq = wsum(kl*kl);
  float nrm = fmaxf(sqrtf(sq), 1e-12f);
  kh[((size_t)b*NKEY_+j)*DH_+lane] = f2bf(kl*(4.0f/nrm));
  vh[((size_t)b*NKEY_+j)*DH_+lane] = f2bf(vl);
}

// ---------------- fused flash attention (MFMA) ----------------
__global__ __launch_bounds__(256) void attn_mfma(const u16* __restrict__ qh, const u16* __restrict__ kh,
    const u16* __restrict__ vh, const float* __restrict__ bias_d, u16* __restrict__ oh){
  __shared__ u16 q_lds[64*72];
  __shared__ u16 k_lds[64*72];
  __shared__ u16 vt_lds[64*72];
  __shared__ float bias_lds[NTOK_];
  __shared__ u16 p_lds[4][16*76];
  int qt = blockIdx.x, h = blockIdx.y, b = blockIdx.z;
  int tid = threadIdx.x, wave = tid>>6, lane = tid&63;
  int g = lane>>4, c = lane&15;

  {
    int i2 = tid >> 2;
    int d0 = (tid & 3) << 4;
    int gi = qt*64 + i2; if (gi >= NTOK_) gi = NTOK_-1;
    const u16* src = qh + (((size_t)(b*NTOK_+gi))*HEADS_ + h)*DH_ + d0;
    uint4 v0 = *(const uint4*)src;
    uint4 v1 = *(const uint4*)(src+8);
    *(uint4*)&q_lds[i2*72 + d0] = v0;
    *(uint4*)&q_lds[i2*72 + d0 + 8] = v1;
  }
  for (int u=tid; u<NTOK_; u+=256) bias_lds[u] = bias_d[h*NTOK_ + u];
  __syncthreads();

  short8 aq[2];
  int rbase = wave*16;
#pragma unroll
  for (int dk=0; dk<2; ++dk)
    aq[dk] = *(const short8*)&q_lds[(rbase + c)*72 + dk*32 + g*8];

  f32x4 o[4];
  float m[4], lsum[4];
#pragma unroll
  for (int dg=0; dg<4; ++dg) o[dg] = (f32x4){0,0,0,0};
#pragma unroll
  for (int t=0; t<4; ++t){ m[t] = -3e38f; lsum[t] = 0.f; }
  int ibase = qt*64 + wave*16;

  for (int jt=0; jt<9; ++jt){
    __syncthreads();
    {
      // K: 4 lanes per row, 16B each (conflict-free b128 writes, padded stride)
      int j2 = tid >> 2, d0k = (tid&3) << 4;
      int gj = jt*64 + j2; if (gj >= NKEY_) gj = NKEY_-1;
      const u16* ks = kh + ((size_t)b*NKEY_ + gj)*DH_ + d0k;
      uint4 k0v = *(const uint4*)ks; uint4 k1v = *(const uint4*)(ks+8);
      *(uint4*)&k_lds[j2*72 + d0k] = k0v;
      *(uint4*)&k_lds[j2*72 + d0k + 8] = k1v;
      // V transpose: thread owns (j = tid&63, d0 = (tid>>6)*16); wave writes
      // contiguous 128B row segments -> conflict-free scalar stores
      int j = tid & 63, d0v = (tid >> 6) << 4;
      int gjv = jt*64 + j; if (gjv >= NKEY_) gjv = NKEY_-1;
      const u16* vs = vh + ((size_t)b*NKEY_ + gjv)*DH_ + d0v;
      u16 tmp[16];
      *(uint4*)&tmp[0] = *(const uint4*)vs;
      *(uint4*)&tmp[8] = *(const uint4*)(vs+8);
#pragma unroll
      for (int e=0; e<16; ++e) vt_lds[(d0v+e)*72 + j] = tmp[e];
    }
    __syncthreads();

    f32x4 s[4];
#pragma unroll
    for (int jc=0; jc<4; ++jc){
      f32x4 z = (f32x4){0,0,0,0};
#pragma unroll
      for (int dk=0; dk<2; ++dk){
        short8 bk = *(const short8*)&k_lds[(jc*16 + c)*72 + dk*32 + g*8];
        z = __builtin_amdgcn_mfma_f32_16x16x32_bf16(aq[dk], bk, z, 0,0,0);
      }
      s[jc] = z;
    }

    float rowmax[4];
#pragma unroll
    for (int t=0; t<4; ++t) rowmax[t] = -3e38f;
#pragma unroll
    for (int jc=0; jc<4; ++jc){
      int j = jt*64 + jc*16 + c;
#pragma unroll
      for (int t=0; t<4; ++t){
        int i = ibase + g*4 + t;
        int d = i - j; if (d < 0) d = 0; if (d > NTOK_-1) d = NTOK_-1;
        float sv = s[jc][t] + bias_lds[d];
        if (j > i+1) sv = -1e30f;
        s[jc][t] = sv;
        rowmax[t] = fmaxf(rowmax[t], sv);
      }
    }
#pragma unroll
    for (int t=0; t<4; ++t){
      float v = rowmax[t];
      v = fmaxf(v, __shfl_xor(v,1));
      v = fmaxf(v, __shfl_xor(v,2));
      v = fmaxf(v, __shfl_xor(v,4));
      v = fmaxf(v, __shfl_xor(v,8));
      rowmax[t] = v;
    }
    float scale_[4], rs[4];
#pragma unroll
    for (int t=0;t<4;++t){
      float mn = fmaxf(m[t], rowmax[t]);
      scale_[t] = __expf(m[t] - mn);
      m[t] = mn;
      rs[t] = 0.f;
    }
    u16* pl = &p_lds[wave][0];
#pragma unroll
    for (int jc=0; jc<4; ++jc){
#pragma unroll
      for (int t=0; t<4; ++t){
        float p = __expf(s[jc][t] - m[t]);
        rs[t] += p;
        pl[(g*4 + t)*76 + jc*16 + c] = f2bf(p);
      }
    }
#pragma unroll
    for (int t=0;t<4;++t){
      float v = rs[t];
      v += __shfl_xor(v,1); v += __shfl_xor(v,2); v += __shfl_xor(v,4); v += __shfl_xor(v,8);
      lsum[t] = lsum[t]*scale_[t] + v;
    }
#pragma unroll
    for (int dg=0; dg<4; ++dg)
#pragma unroll
      for (int t=0;t<4;++t) o[dg][t] *= scale_[t];
#pragma unroll
    for (int ks=0; ks<2; ++ks){
      short8 ap = *(const short8*)&pl[c*76 + ks*32 + g*8];
#pragma unroll
      for (int dg=0; dg<4; ++dg){
        short8 bv = *(const short8*)&vt_lds[(dg*16 + c)*72 + ks*32 + g*8];
        o[dg] = __builtin_amdgcn_mfma_f32_16x16x32_bf16(ap, bv, o[dg], 0,0,0);
      }
    }
  }

#pragma unroll
  for (int t=0;t<4;++t){
    int i = ibase + g*4 + t;
    if (i < NTOK_){
      float inv = 1.0f / lsum[t];
#pragma unroll
      for (int dg=0; dg<4; ++dg)
        oh[(((size_t)(b*NTOK_+i))*HEADS_ + h)*DH_ + dg*16 + c] = f2bf(o[dg][t] * inv);
    }
  }
}

extern "C" void kernel_launch(void* const* d_in, const int* in_sizes, int n_in,
                              void* d_out, int out_size, void* d_ws, size_t ws_size,
                              hipStream_t stream) {
  const float* image = (const float*)d_in[0];
  const float* brain = (const float*)d_in[1];
  const int*   tsteps= (const int*)  d_in[2];
  const float* lq    = (const float*)d_in[3];
  const float* t_w1  = (const float*)d_in[4];
  const float* t_b1  = (const float*)d_in[5];
  const float* t_w2  = (const float*)d_in[6];
  const float* t_b2  = (const float*)d_in[7];
  const float* t_w3  = (const float*)d_in[8];
  const float* t_b3  = (const float*)d_in[9];
  const float* relpos= (const float*)d_in[10];
  const float* anorm = (const float*)d_in[11];
  const float* Wq    = (const float*)d_in[12];
  const float* Wkv   = (const float*)d_in[13];
  const float* nkv   = (const float*)d_in[14];
  const float* Wo    = (const float*)d_in[15];
  const float* aoutg = (const float*)d_in[16];
  const float* fng   = (const float*)d_in[17];
  const float* Win   = (const float*)d_in[18];
  const float* Wout  = (const float*)d_in[19];
  const float* fing  = (const float*)d_in[20];
  const float* Wproj = (const float*)d_in[21];
  float* out = (float*)d_out;

  float* p = (float*)d_ws;
  auto alloc = [&](size_t nfl){ float* r = p; p += nfl; return r; };
  const size_t SZ_X = (size_t)NROW_*DIM_;
  float* x     = alloc(SZ_X);
  float* ubu   = alloc((size_t)NROW_*FFI_/2);      // union: tb f32 | ub bf16
  u16*   xnh   = (u16*)alloc(SZ_X/2);
  u16*   qh    = (u16*)alloc(SZ_X/2);
  u16*   kvb   = (u16*)alloc((size_t)NROW_*128/2);
  u16*   kh    = (u16*)alloc((size_t)B_*NKEY_*DH_/2);
  u16*   vh    = (u16*)alloc((size_t)B_*NKEY_*DH_/2);
  u16*   oh    = (u16*)alloc(SZ_X/2);
  u16*   WqT   = (u16*)alloc((size_t)DEPTH_*DIM_*DIM_/2);
  u16*   WkvT  = (u16*)alloc((size_t)DEPTH_*DIM_*128/2);
  u16*   WoT   = (u16*)alloc((size_t)DEPTH_*DIM_*DIM_/2);
  u16*   WinT  = (u16*)alloc((size_t)DEPTH_*DIM_*2*FFI_/2);
  u16*   WoutT = (u16*)alloc((size_t)DEPTH_*FFI_*DIM_/2);
  u16*   WprojT= (u16*)alloc((size_t)DIM_*DIM_/2);
  float* pe    = alloc(8*768);
  float* h1    = alloc(8*1536);
  float* h2    = alloc(8*1536);
  float* temb  = alloc(8*768);
  float* biasd = alloc(HEADS_*NTOK_ + 4);
  float* tb    = ubu;
  u16*   ub    = (u16*)ubu;

  // weight transposes (f32 -> bf16 [N][K])
  transpose_bf16<<<dim3(DIM_/32, DIM_/32, DEPTH_),256,0,stream>>>(Wq, WqT, DIM_, DIM_);
  transpose_bf16<<<dim3(128/32,  DIM_/32, DEPTH_),256,0,stream>>>(Wkv, WkvT, DIM_, 128);
  transpose_bf16<<<dim3(DIM_/32, DIM_/32, DEPTH_),256,0,stream>>>(Wo, WoT, DIM_, DIM_);
  transpose_bf16<<<dim3(2*FFI_/32, DIM_/32, DEPTH_),256,0,stream>>>(Win, WinT, DIM_, 2*FFI_);
  transpose_bf16<<<dim3(DIM_/32, FFI_/32, DEPTH_),256,0,stream>>>(Wout, WoutT, FFI_, DIM_);
  transpose_bf16<<<dim3(DIM_/32, DIM_/32, 1),256,0,stream>>>(Wproj, WprojT, DIM_, DIM_);

  // time embedding (split-K, bias-init + atomic reduce; silu folded into input reads)
  pe_kernel<<<B_,256,0,stream>>>(tsteps, pe);
  fc_init<<<(8*1536+255)/256,256,0,stream>>>(t_b1, h1, 1536);
  fc_split<<<dim3(1536/64, 768/128),256,0,stream>>>(pe, t_w1, h1, 768, 1536, 0);
  fc_init<<<(8*1536+255)/256,256,0,stream>>>(t_b2, h2, 1536);
  fc_split<<<dim3(1536/64, 1536/128),256,0,stream>>>(h1, t_w2, h2, 1536, 1536, 1);
  fc_init<<<(8*768+255)/256,256,0,stream>>>(t_b3, temb, 768);
  fc_split<<<dim3(768/64, 1536/128),256,0,stream>>>(h2, t_w3, temb, 1536, 768, 1);

  build_tokens<<<NROW_,256,0,stream>>>(brain, image, lq, temb, x);
  bias_delta<<<(NTOK_+255)/256,256,0,stream>>>(relpos, biasd);

  for (int l=0; l<DEPTH_; ++l){
    ln_to_bf16<<<NROW_,256,0,stream>>>(x, anorm + (size_t)l*DIM_, xnh, 0);
    gemm_bf16<0><<<dim3(6,33),256,0,stream>>>(xnh, WqT + (size_t)l*DIM_*DIM_, NROW_, DIM_, DIM_,
                                              nullptr, qh, nullptr, 1, 0);
    gemm_bf16<0><<<dim3(1,33),256,0,stream>>>(xnh, WkvT + (size_t)l*DIM_*128, NROW_, 128, DIM_,
                                              nullptr, kvb, nullptr, 1, 0);
    qprep<<<NROW_*HEADS_/4,256,0,stream>>>(qh);
    kvprep<<<B_*NKEY_/4,256,0,stream>>>(kvb, nkv + (size_t)l*2*DH_, kh, vh);
    attn_mfma<<<dim3(9,HEADS_,B_),256,0,stream>>>(qh, kh, vh, biasd, oh);
    gemm_bf16<0><<<dim3(6,33),256,0,stream>>>(oh, WoT + (size_t)l*DIM_*DIM_, NROW_, DIM_, DIM_,
                                              tb, nullptr, nullptr, 0, 0);
    ln_resid<<<NROW_,256,0,stream>>>(tb, aoutg + (size_t)l*DIM_, x);
    ln_to_bf16<<<NROW_,256,0,stream>>>(x, fng + (size_t)l*DIM_, xnh, 0);
    gemm_bf16<1><<<dim3(24,33),256,0,stream>>>(xnh, WinT + (size_t)l*DIM_*2*FFI_, NROW_, FFI_, DIM_,
                                               nullptr, ub, nullptr, 3, 0);
    gemm_bf16<0><<<dim3(6,33),256,0,stream>>>(ub, WoutT + (size_t)l*FFI_*DIM_, NROW_, DIM_, FFI_,
                                              nullptr, nullptr, x, 2, 0);
  }

  ln_to_bf16<<<NROW_,256,0,stream>>>(x, fing, xnh, 1);
  gemm_bf16<0><<<dim3(6,17),256,0,stream>>>(xnh, WprojT, B_*NT_, DIM_, DIM_,
                                            out, nullptr, nullptr, 0, 1);
}

// Round 7
// 1983.570 us; speedup vs baseline: 5.4759x; 1.3171x over previous
//
#include <hip/hip_runtime.h>
#include <cfloat>
#include <cmath>

#define B_      8
#define NT_     257
#define DIM_    768
#define HEADS_  12
#define DH_     64
#define DEPTH_  6
#define NTOK_   515        // brain(257) + time(1) + image(257)
#define NKEY_   516        // + null kv
#define NROW_   (B_*NTOK_) // 4120
#define FFI_    3072
#define QKV_N   896        // 768 q + 128 kv

typedef unsigned short u16;
typedef __attribute__((ext_vector_type(8))) short short8;
typedef __attribute__((ext_vector_type(4))) float f32x4;

__device__ __forceinline__ u16 f2bf(float f){
  union { float f; unsigned u; } v; v.f = f;
  unsigned r = v.u + 0x7fffu + ((v.u >> 16) & 1u);
  return (u16)(r >> 16);
}
__device__ __forceinline__ float bf2f(u16 h){
  union { unsigned u; float f; } v; v.u = ((unsigned)h) << 16;
  return v.f;
}
__device__ __forceinline__ float wsum(float v){
#pragma unroll
  for (int o=32;o;o>>=1) v += __shfl_xor(v,o);
  return v;
}
__device__ __forceinline__ float wmax(float v){
#pragma unroll
  for (int o=32;o;o>>=1) v = fmaxf(v,__shfl_xor(v,o));
  return v;
}
// async global->LDS, 16B per lane; lp must be wave-uniform chunk base
__device__ __forceinline__ void gload16(const u16* gp, u16* lp){
  __builtin_amdgcn_global_load_lds(
      (const __attribute__((address_space(1))) unsigned int*)gp,
      (__attribute__((address_space(3))) unsigned int*)lp, 16, 0, 0);
}

// ---------------- transpose f32 [K][N] -> bf16 [N][K] (+optional row remap) ----------------
// pair=1: Win pairing: src col n<3072 -> row (n/64)*128 + n%64 ; n>=3072 -> (n'/64)*128+64+n'%64
__global__ __launch_bounds__(256) void transpose_bf16(const float* __restrict__ src, u16* __restrict__ dst,
    int K, int N, long src_z, long dst_z, int row_off, int pair){
  __shared__ float tile[32][33];
  src += (size_t)blockIdx.z * src_z;
  dst += (size_t)blockIdx.z * dst_z;
  int c0 = blockIdx.x*32, r0 = blockIdx.y*32;
  int tx = threadIdx.x & 31, ty = threadIdx.x >> 5;
#pragma unroll
  for (int u=0; u<4; ++u){
    int r = ty*4 + u;
    tile[r][tx] = src[(size_t)(r0 + r)*N + c0 + tx];
  }
  __syncthreads();
#pragma unroll
  for (int u=0; u<4; ++u){
    int r = ty*4 + u;
    int n = c0 + r;
    int drow;
    if (pair){
      if (n < FFI_) drow = ((n>>6)<<7) + (n&63);
      else { int n2 = n - FFI_; drow = ((n2>>6)<<7) + 64 + (n2&63); }
    } else drow = row_off + n;
    dst[(size_t)drow*K + r0 + tx] = f2bf(tile[tx][r]);
  }
}

// ---------------- time-embedding ----------------
__global__ __launch_bounds__(256) void pe_kernel(const int* __restrict__ ts, float* __restrict__ pe){
  int b = blockIdx.x;
  float t = (float)ts[b];
  const float cc = -logf(10000.0f)/383.0f;
  for (int i=threadIdx.x; i<768; i+=256){
    int k = (i<384)? i : i-384;
    float f = __expf((float)k*cc);
    pe[b*768+i] = (i<384)? sinf(t*f) : cosf(t*f);
  }
}
__global__ __launch_bounds__(256) void fc_init(const float* __restrict__ bias, float* __restrict__ out, int N){
  int i = blockIdx.x*256 + threadIdx.x;
  if (i < 8*N) out[i] = bias[i % N];
}
// split-K fc: out[8][N] += in(8xK slice) @ W ; silu applied to INPUT if act_in
__global__ __launch_bounds__(256) void fc_split(const float* __restrict__ in, const float* __restrict__ W,
    float* __restrict__ out, int K, int N, int act_in){
  __shared__ float in_lds[8][128];
  __shared__ float red[4][8][64];
  int kg = threadIdx.x >> 6;
  int c  = threadIdx.x & 63;
  int col = blockIdx.x*64 + c;
  int k0 = blockIdx.y*128;
  for (int idx = threadIdx.x; idx < 8*128; idx += 256){
    int r = idx >> 7, k = idx & 127;
    float v = in[(size_t)r*K + k0 + k];
    if (act_in) v = v/(1.0f+__expf(-v));
    in_lds[r][k] = v;
  }
  __syncthreads();
  float acc[8] = {0,0,0,0,0,0,0,0};
  const float* wp = W + (size_t)(k0 + kg*32)*N + col;
#pragma unroll 4
  for (int kk=0; kk<32; ++kk){
    float w = wp[(size_t)kk*N];
#pragma unroll
    for (int r=0;r<8;++r) acc[r] += in_lds[r][kg*32+kk]*w;
  }
#pragma unroll
  for (int r=0;r<8;++r) red[kg][r][c] = acc[r];
  __syncthreads();
  for (int p2 = threadIdx.x; p2 < 512; p2 += 256){
    int r = p2 >> 6, cc = p2 & 63;
    float s = red[0][r][cc]+red[1][r][cc]+red[2][r][cc]+red[3][r][cc];
    atomicAdd(out + (size_t)r*N + blockIdx.x*64 + cc, s);
  }
}

// ---------------- build token sequence (f32) ----------------
__global__ __launch_bounds__(256) void build_tokens(const float* __restrict__ brain,
    const float* __restrict__ image, const float* __restrict__ lq,
    const float* __restrict__ temb, float* __restrict__ x){
  int row = blockIdx.x;
  int b = row / NTOK_, t = row % NTOK_;
  int tid = threadIdx.x;
#pragma unroll
  for (int u=0;u<3;++u){
    int d = tid + u*256;
    float val;
    if (t < 257)      val = brain[((size_t)(b*257+t))*DIM_ + d];
    else if (t == 257) val = temb[(size_t)b*DIM_ + d];
    else               val = image[((size_t)(b*257 + (t-258)))*DIM_ + d] + lq[((size_t)(t-258))*DIM_ + d];
    x[(size_t)row*DIM_ + d] = val;
  }
}

// ---------------- rel-pos bias by delta ----------------
__global__ __launch_bounds__(256) void bias_delta(const float* __restrict__ emb, float* __restrict__ bias_d){
  int d = blockIdx.x*256 + threadIdx.x;
  if (d >= NTOK_) return;
  int bucket;
  if (d < 16) bucket = d;
  else {
    int lg = 16 + (int)(logf((float)d * (1.0f/16.0f)) * (16.0f/logf(8.0f)));
    bucket = lg < 31 ? lg : 31;
  }
  for (int h=0; h<HEADS_; ++h) bias_d[h*NTOK_ + d] = emb[bucket*HEADS_ + h];
}

// ---------------- LayerNorm -> bf16 ----------------
__global__ __launch_bounds__(256) void ln_to_bf16(const float* __restrict__ src, const float* __restrict__ gamma,
    u16* __restrict__ dst, int stable){
  __shared__ float red[4];
  int row = blockIdx.x;
  const float* s = src + (size_t)row*DIM_;
  int tid = threadIdx.x, wv = tid>>6, ln = tid&63;
  float v0 = s[tid], v1 = s[tid+256], v2 = s[tid+512];
  if (stable){
    float m = wmax(fmaxf(fmaxf(v0,v1),v2));
    if (ln==0) red[wv]=m;
    __syncthreads();
    m = fmaxf(fmaxf(red[0],red[1]),fmaxf(red[2],red[3]));
    __syncthreads();
    float inv = 1.0f/m; v0*=inv; v1*=inv; v2*=inv;
  }
  float sum = wsum(v0+v1+v2);
  if (ln==0) red[wv]=sum;
  __syncthreads();
  sum = red[0]+red[1]+red[2]+red[3];
  __syncthreads();
  float mean = sum * (1.0f/DIM_);
  float d0=v0-mean, d1=v1-mean, d2=v2-mean;
  float sq = wsum(d0*d0+d1*d1+d2*d2);
  if (ln==0) red[wv]=sq;
  __syncthreads();
  sq = red[0]+red[1]+red[2]+red[3];
  float inv = rsqrtf(sq*(1.0f/DIM_) + 1e-5f);
  u16* d = dst + (size_t)row*DIM_;
  d[tid]     = f2bf(d0*inv*gamma[tid]);
  d[tid+256] = f2bf(d1*inv*gamma[tid+256]);
  d[tid+512] = f2bf(d2*inv*gamma[tid+512]);
}

// ---------------- x += LN(src) (f32) ----------------
__global__ __launch_bounds__(256) void ln_resid(const float* __restrict__ src, const float* __restrict__ gamma,
    float* __restrict__ x){
  __shared__ float red[4];
  int row = blockIdx.x;
  const float* s = src + (size_t)row*DIM_;
  int tid = threadIdx.x, wv = tid>>6, ln = tid&63;
  float v0 = s[tid], v1 = s[tid+256], v2 = s[tid+512];
  float sum = wsum(v0+v1+v2);
  if (ln==0) red[wv]=sum;
  __syncthreads();
  sum = red[0]+red[1]+red[2]+red[3];
  __syncthreads();
  float mean = sum * (1.0f/DIM_);
  float d0=v0-mean, d1=v1-mean, d2=v2-mean;
  float sq = wsum(d0*d0+d1*d1+d2*d2);
  if (ln==0) red[wv]=sq;
  __syncthreads();
  sq = red[0]+red[1]+red[2]+red[3];
  float inv = rsqrtf(sq*(1.0f/DIM_) + 1e-5f);
  float* xr = x + (size_t)row*DIM_;
  xr[tid]     += d0*inv*gamma[tid];
  xr[tid+256] += d1*inv*gamma[tid+256];
  xr[tid+512] += d2*inv*gamma[tid+512];
}

// ---------------- bf16 MFMA GEMM ----------------
// A[M][K] bf16, Bt[*][K] bf16 -> C[M][N]. LDS [128][32] linear (gload_lds dest),
// XOR swizzle slot s^((row>>1)&3) on source + read (involution).
// GATED=1: Bt is the PAIRED Win layout (row block 128 = 64 a-rows + 64 g-rows);
// block outputs 64 cols: a-waves (wc=0) hold a, g-waves (wc=64) hold gate;
// epilogue: gate -> silu -> LDS -> a-waves multiply. 64 AGPR/wave everywhere.
template<int GATED>
__global__ __launch_bounds__(256, 2) void gemm_bf16(const u16* __restrict__ A, const u16* __restrict__ Bt,
    int M, int N, int K, float* __restrict__ Cf, u16* __restrict__ Ch,
    float* __restrict__ Xres, int mode, int gather){
  __shared__ u16 smem[GATED ? 9216 : 8192];
  u16* Al = smem;
  u16* Bl = smem + 4096;
  int tid = threadIdx.x;
  int lane = tid & 63, wave = tid >> 6;
  int g = lane >> 4, c = lane & 15;
  int row0 = blockIdx.y * 128;
  int wr = (wave >> 1) * 64, wc = (wave & 1) * 64;

  f32x4 acc[4][4];
#pragma unroll
  for (int i=0;i<4;++i)
#pragma unroll
    for (int j=0;j<4;++j) acc[i][j] = (f32x4){0,0,0,0};

  auto stage = [&](const u16* __restrict__ src, int r0, int rmax, int ld, int k0, u16* lds, bool remap){
#pragma unroll
    for (int u=0; u<2; ++u){
      int idx = u*256 + tid;          // 0..511 (16B units)
      int r = idx >> 2;               // tile row 0..127
      int s = idx & 3;                // 16B slot
      int ss = s ^ ((r>>1)&3);        // inverse swizzle on source
      int rr = r0 + r; if (rr >= rmax) rr = rmax-1;
      if (remap){ int bb = rr / NT_, t = rr - bb*NT_; rr = bb*NTOK_ + 258 + t; }
      gload16(src + (size_t)rr*ld + k0 + ss*8, lds + (size_t)(u*256 + wave*64)*8);
    }
  };

  int brow0 = blockIdx.x * 128;
  int brmax = GATED ? 2*FFI_ : N;   // paired Win has 6144 rows
  for (int k0 = 0; k0 < K; k0 += 32){
    stage(A, row0, M, K, k0, Al, gather != 0);
    stage(Bt, brow0, brmax, K, k0, Bl, false);
    __syncthreads();
    short8 af[4], bf[4];
    int sw = (g ^ ((c>>1)&3)) * 8;    // swizzled slot offset
#pragma unroll
    for (int mi=0; mi<4; ++mi)
      af[mi] = *(const short8*)(Al + (wr + mi*16 + c)*32 + sw);
#pragma unroll
    for (int ni=0; ni<4; ++ni)
      bf[ni] = *(const short8*)(Bl + (wc + ni*16 + c)*32 + sw);
#pragma unroll
    for (int mi=0; mi<4; ++mi)
#pragma unroll
      for (int ni=0; ni<4; ++ni)
        acc[mi][ni] = __builtin_amdgcn_mfma_f32_16x16x32_bf16(af[mi], bf[ni], acc[mi][ni], 0,0,0);
    __syncthreads();
  }

  if constexpr (GATED){
    u16* GL = smem;                 // [128][72] bf16 gate overlay (staging dead)
    if (wave & 1){
#pragma unroll
      for (int mi=0;mi<4;++mi)
#pragma unroll
        for (int t=0;t<4;++t){
          int rl = wr + mi*16 + g*4 + t;
#pragma unroll
          for (int ni=0;ni<4;++ni){
            float gv = acc[mi][ni][t];
            GL[rl*72 + ni*16 + c] = f2bf(gv/(1.0f+__expf(-gv)));
          }
        }
    }
    __syncthreads();
    if (!(wave & 1)){
#pragma unroll
      for (int mi=0;mi<4;++mi)
#pragma unroll
        for (int t=0;t<4;++t){
          int rl = wr + mi*16 + g*4 + t;
          int r = row0 + rl;
          if (r < M){
#pragma unroll
            for (int ni=0;ni<4;++ni){
              int cc = blockIdx.x*64 + ni*16 + c;
              Ch[(size_t)r*N + cc] = f2bf(acc[mi][ni][t]*bf2f(GL[rl*72 + ni*16 + c]));
            }
          }
        }
    }
  } else {
#pragma unroll
    for (int mi=0; mi<4; ++mi){
#pragma unroll
      for (int t=0; t<4; ++t){
        int r = row0 + wr + mi*16 + g*4 + t;
        if (r < M){
#pragma unroll
          for (int ni=0; ni<4; ++ni){
            int cc = blockIdx.x*128 + wc + ni*16 + c;
            float v = acc[mi][ni][t];
            if (mode == 0)      Cf[(size_t)r*N + cc] = v;
            else if (mode == 1) Ch[(size_t)r*N + cc] = f2bf(v);
            else                Xres[(size_t)r*N + cc] += v;
          }
        }
      }
    }
  }
}

// ---------------- RoPE + l2norm + scale on q (in qkv buffer, stride 896) ----------------
__global__ __launch_bounds__(256) void qprep(u16* __restrict__ qkv){
  int vec = blockIdx.x*4 + (threadIdx.x>>6);
  int lane = threadIdx.x & 63;
  if (vec >= NROW_*HEADS_) return;
  int row = vec / HEADS_, h = vec - row*HEADS_;
  int n = row % NTOK_;
  u16* p = qkv + (size_t)row*QKV_N + h*64 + lane;
  float v = bf2f(*p);
  float t1 = __shfl(v, lane & 62);
  float t2 = __shfl(v, lane | 1);
  float out = v;
  if (lane < 32){
    int ii = lane >> 1;
    float invf = __expf(-logf(10000.0f) * (float)ii / 16.0f);
    float fr = (float)n * invf;
    float cs = cosf(fr), sn = sinf(fr);
    out = (lane & 1) ? (t1*sn + t2*cs) : (t1*cs - t2*sn);
  }
  float sq = wsum(out*out);
  float nrm = fmaxf(sqrtf(sq), 1e-12f);
  *p = f2bf(out * (4.0f/nrm));
}

// ---------------- build k/v (bf16) with null at j=0; RoPE+l2norm on k ----------------
__global__ __launch_bounds__(256) void kvprep(const u16* __restrict__ qkv, const float* __restrict__ nullkv,
    u16* __restrict__ kh, u16* __restrict__ vh){
  int idx = blockIdx.x*4 + (threadIdx.x>>6);
  if (idx >= B_*NKEY_) return;
  int b = idx / NKEY_, j = idx % NKEY_;
  int lane = threadIdx.x & 63;
  float kl, vl;
  if (j == 0){ kl = nullkv[lane]; vl = nullkv[DH_+lane]; }
  else {
    const u16* row = qkv + (size_t)(b*NTOK_ + (j-1))*QKV_N + 768;
    kl = bf2f(row[lane]); vl = bf2f(row[DH_+lane]);
  }
  float t1 = __shfl(kl, lane & 62);
  float t2 = __shfl(kl, lane | 1);
  if (j > 0 && lane < 32){
    int ii = lane >> 1;
    float invf = __expf(-logf(10000.0f) * (float)ii / 16.0f);
    float fr = (float)(j-1) * invf;
    float cs = cosf(fr), sn = sinf(fr);
    kl = (lane & 1) ? (t1*sn + t2*cs) : (t1*cs - t2*sn);
  }
  float sq = wsum(kl*kl);
  float nrm = fmaxf(sqrtf(sq), 1e-12f);
  kh[((size_t)b*NKEY_+j)*DH_+lane] = f2bf(kl*(4.0f/nrm));
  vh[((size_t)b*NKEY_+j)*DH_+lane] = f2bf(vl);
}

// ---------------- fused flash attention (MFMA) ----------------
__global__ __launch_bounds__(256) void attn_mfma(const u16* __restrict__ qkv, const u16* __restrict__ kh,
    const u16* __restrict__ vh, const float* __restrict__ bias_d, u16* __restrict__ oh){
  __shared__ u16 q_lds[64*72];
  __shared__ u16 k_lds[64*72];
  __shared__ u16 vt_lds[64*72];
  __shared__ float bias_lds[NTOK_];
  __shared__ u16 p_lds[4][16*76];
  int qt = blockIdx.x, h = blockIdx.y, b = blockIdx.z;
  int tid = threadIdx.x, wave = tid>>6, lane = tid&63;
  int g = lane>>4, c = lane&15;

  {
    int i2 = tid >> 2;
    int d0 = (tid & 3) << 4;
    int gi = qt*64 + i2; if (gi >= NTOK_) gi = NTOK_-1;
    const u16* src = qkv + ((size_t)(b*NTOK_+gi))*QKV_N + h*64 + d0;
    uint4 v0 = *(const uint4*)src;
    uint4 v1 = *(const uint4*)(src+8);
    *(uint4*)&q_lds[i2*72 + d0] = v0;
    *(uint4*)&q_lds[i2*72 + d0 + 8] = v1;
  }
  for (int u=tid; u<NTOK_; u+=256) bias_lds[u] = bias_d[h*NTOK_ + u];
  __syncthreads();

  short8 aq[2];
  int rbase = wave*16;
#pragma unroll
  for (int dk=0; dk<2; ++dk)
    aq[dk] = *(const short8*)&q_lds[(rbase + c)*72 + dk*32 + g*8];

  f32x4 o[4];
  float m[4], lsum[4];
#pragma unroll
  for (int dg=0; dg<4; ++dg) o[dg] = (f32x4){0,0,0,0};
#pragma unroll
  for (int t=0; t<4; ++t){ m[t] = -3e38f; lsum[t] = 0.f; }
  int ibase = qt*64 + wave*16;

  for (int jt=0; jt<9; ++jt){
    __syncthreads();
    {
      int j2 = tid >> 2, d0k = (tid&3) << 4;
      int gj = jt*64 + j2; if (gj >= NKEY_) gj = NKEY_-1;
      const u16* ks = kh + ((size_t)b*NKEY_ + gj)*DH_ + d0k;
      uint4 k0v = *(const uint4*)ks; uint4 k1v = *(const uint4*)(ks+8);
      *(uint4*)&k_lds[j2*72 + d0k] = k0v;
      *(uint4*)&k_lds[j2*72 + d0k + 8] = k1v;
      int j = tid & 63, d0v = (tid >> 6) << 4;
      int gjv = jt*64 + j; if (gjv >= NKEY_) gjv = NKEY_-1;
      const u16* vs = vh + ((size_t)b*NKEY_ + gjv)*DH_ + d0v;
      u16 tmp[16];
      *(uint4*)&tmp[0] = *(const uint4*)vs;
      *(uint4*)&tmp[8] = *(const uint4*)(vs+8);
#pragma unroll
      for (int e=0; e<16; ++e) vt_lds[(d0v+e)*72 + j] = tmp[e];
    }
    __syncthreads();

    f32x4 s[4];
#pragma unroll
    for (int jc=0; jc<4; ++jc){
      f32x4 z = (f32x4){0,0,0,0};
#pragma unroll
      for (int dk=0; dk<2; ++dk){
        short8 bk = *(const short8*)&k_lds[(jc*16 + c)*72 + dk*32 + g*8];
        z = __builtin_amdgcn_mfma_f32_16x16x32_bf16(aq[dk], bk, z, 0,0,0);
      }
      s[jc] = z;
    }

    float rowmax[4];
#pragma unroll
    for (int t=0; t<4; ++t) rowmax[t] = -3e38f;
#pragma unroll
    for (int jc=0; jc<4; ++jc){
      int j = jt*64 + jc*16 + c;
#pragma unroll
      for (int t=0; t<4; ++t){
        int i = ibase + g*4 + t;
        int d = i - j; if (d < 0) d = 0; if (d > NTOK_-1) d = NTOK_-1;
        float sv = s[jc][t] + bias_lds[d];
        if (j > i+1) sv = -1e30f;
        s[jc][t] = sv;
        rowmax[t] = fmaxf(rowmax[t], sv);
      }
    }
#pragma unroll
    for (int t=0; t<4; ++t){
      float v = rowmax[t];
      v = fmaxf(v, __shfl_xor(v,1));
      v = fmaxf(v, __shfl_xor(v,2));
      v = fmaxf(v, __shfl_xor(v,4));
      v = fmaxf(v, __shfl_xor(v,8));
      rowmax[t] = v;
    }
    float scale_[4], rs[4];
#pragma unroll
    for (int t=0;t<4;++t){
      float mn = fmaxf(m[t], rowmax[t]);
      scale_[t] = __expf(m[t] - mn);
      m[t] = mn;
      rs[t] = 0.f;
    }
    u16* pl = &p_lds[wave][0];
#pragma unroll
    for (int jc=0; jc<4; ++jc){
#pragma unroll
      for (int t=0; t<4; ++t){
        float p = __expf(s[jc][t] - m[t]);
        rs[t] += p;
        pl[(g*4 + t)*76 + jc*16 + c] = f2bf(p);
      }
    }
#pragma unroll
    for (int t=0;t<4;++t){
      float v = rs[t];
      v += __shfl_xor(v,1); v += __shfl_xor(v,2); v += __shfl_xor(v,4); v += __shfl_xor(v,8);
      lsum[t] = lsum[t]*scale_[t] + v;
    }
#pragma unroll
    for (int dg=0; dg<4; ++dg)
#pragma unroll
      for (int t=0;t<4;++t) o[dg][t] *= scale_[t];
#pragma unroll
    for (int ks=0; ks<2; ++ks){
      short8 ap = *(const short8*)&pl[c*76 + ks*32 + g*8];
#pragma unroll
      for (int dg=0; dg<4; ++dg){
        short8 bv = *(const short8*)&vt_lds[(dg*16 + c)*72 + ks*32 + g*8];
        o[dg] = __builtin_amdgcn_mfma_f32_16x16x32_bf16(ap, bv, o[dg], 0,0,0);
      }
    }
  }

#pragma unroll
  for (int t=0;t<4;++t){
    int i = ibase + g*4 + t;
    if (i < NTOK_){
      float inv = 1.0f / lsum[t];
#pragma unroll
      for (int dg=0; dg<4; ++dg)
        oh[(((size_t)(b*NTOK_+i))*HEADS_ + h)*DH_ + dg*16 + c] = f2bf(o[dg][t] * inv);
    }
  }
}

extern "C" void kernel_launch(void* const* d_in, const int* in_sizes, int n_in,
                              void* d_out, int out_size, void* d_ws, size_t ws_size,
                              hipStream_t stream) {
  const float* image = (const float*)d_in[0];
  const float* brain = (const float*)d_in[1];
  const int*   tsteps= (const int*)  d_in[2];
  const float* lq    = (const float*)d_in[3];
  const float* t_w1  = (const float*)d_in[4];
  const float* t_b1  = (const float*)d_in[5];
  const float* t_w2  = (const float*)d_in[6];
  const float* t_b2  = (const float*)d_in[7];
  const float* t_w3  = (const float*)d_in[8];
  const float* t_b3  = (const float*)d_in[9];
  const float* relpos= (const float*)d_in[10];
  const float* anorm = (const float*)d_in[11];
  const float* Wq    = (const float*)d_in[12];
  const float* Wkv   = (const float*)d_in[13];
  const float* nkv   = (const float*)d_in[14];
  const float* Wo    = (const float*)d_in[15];
  const float* aoutg = (const float*)d_in[16];
  const float* fng   = (const float*)d_in[17];
  const float* Win   = (const float*)d_in[18];
  const float* Wout  = (const float*)d_in[19];
  const float* fing  = (const float*)d_in[20];
  const float* Wproj = (const float*)d_in[21];
  float* out = (float*)d_out;

  float* p = (float*)d_ws;
  auto alloc = [&](size_t nfl){ float* r = p; p += nfl; return r; };
  const size_t SZ_X = (size_t)NROW_*DIM_;
  float* x     = alloc(SZ_X);
  float* ubu   = alloc((size_t)NROW_*FFI_/2);      // union: tb f32 | ub bf16
  u16*   xnh   = (u16*)alloc(SZ_X/2);
  u16*   qkvh  = (u16*)alloc((size_t)NROW_*QKV_N/2);
  u16*   kh    = (u16*)alloc((size_t)B_*NKEY_*DH_/2);
  u16*   vh    = (u16*)alloc((size_t)B_*NKEY_*DH_/2);
  u16*   oh    = (u16*)alloc(SZ_X/2);
  u16*   WqkvT = (u16*)alloc((size_t)DEPTH_*QKV_N*DIM_/2);
  u16*   WoT   = (u16*)alloc((size_t)DEPTH_*DIM_*DIM_/2);
  u16*   WinP  = (u16*)alloc((size_t)DEPTH_*DIM_*2*FFI_/2);
  u16*   WoutT = (u16*)alloc((size_t)DEPTH_*FFI_*DIM_/2);
  u16*   WprojT= (u16*)alloc((size_t)DIM_*DIM_/2);
  float* pe    = alloc(8*768);
  float* h1    = alloc(8*1536);
  float* h2    = alloc(8*1536);
  float* temb  = alloc(8*768);
  float* biasd = alloc(HEADS_*NTOK_ + 4);
  float* tb    = ubu;
  u16*   ub    = (u16*)ubu;

  // weight transposes (f32 -> bf16 [N][K]); Wq+Wkv into one [896][768]; Win paired
  transpose_bf16<<<dim3(DIM_/32, DIM_/32, DEPTH_),256,0,stream>>>(Wq, WqkvT, DIM_, DIM_,
      (long)DIM_*DIM_, (long)QKV_N*DIM_, 0, 0);
  transpose_bf16<<<dim3(128/32, DIM_/32, DEPTH_),256,0,stream>>>(Wkv, WqkvT, DIM_, 128,
      (long)DIM_*128, (long)QKV_N*DIM_, 768, 0);
  transpose_bf16<<<dim3(DIM_/32, DIM_/32, DEPTH_),256,0,stream>>>(Wo, WoT, DIM_, DIM_,
      (long)DIM_*DIM_, (long)DIM_*DIM_, 0, 0);
  transpose_bf16<<<dim3(2*FFI_/32, DIM_/32, DEPTH_),256,0,stream>>>(Win, WinP, DIM_, 2*FFI_,
      (long)DIM_*2*FFI_, (long)DIM_*2*FFI_, 0, 1);
  transpose_bf16<<<dim3(DIM_/32, FFI_/32, DEPTH_),256,0,stream>>>(Wout, WoutT, FFI_, DIM_,
      (long)FFI_*DIM_, (long)FFI_*DIM_, 0, 0);
  transpose_bf16<<<dim3(DIM_/32, DIM_/32, 1),256,0,stream>>>(Wproj, WprojT, DIM_, DIM_,
      (long)DIM_*DIM_, (long)DIM_*DIM_, 0, 0);

  // time embedding (split-K, bias-init + atomic reduce; silu folded into input reads)
  pe_kernel<<<B_,256,0,stream>>>(tsteps, pe);
  fc_init<<<(8*1536+255)/256,256,0,stream>>>(t_b1, h1, 1536);
  fc_split<<<dim3(1536/64, 768/128),256,0,stream>>>(pe, t_w1, h1, 768, 1536, 0);
  fc_init<<<(8*1536+255)/256,256,0,stream>>>(t_b2, h2, 1536);
  fc_split<<<dim3(1536/64, 1536/128),256,0,stream>>>(h1, t_w2, h2, 1536, 1536, 1);
  fc_init<<<(8*768+255)/256,256,0,stream>>>(t_b3, temb, 768);
  fc_split<<<dim3(768/64, 1536/128),256,0,stream>>>(h2, t_w3, temb, 1536, 768, 1);

  build_tokens<<<NROW_,256,0,stream>>>(brain, image, lq, temb, x);
  bias_delta<<<(NTOK_+255)/256,256,0,stream>>>(relpos, biasd);

  for (int l=0; l<DEPTH_; ++l){
    ln_to_bf16<<<NROW_,256,0,stream>>>(x, anorm + (size_t)l*DIM_, xnh, 0);
    gemm_bf16<0><<<dim3(7,33),256,0,stream>>>(xnh, WqkvT + (size_t)l*QKV_N*DIM_, NROW_, QKV_N, DIM_,
                                              nullptr, qkvh, nullptr, 1, 0);
    qprep<<<NROW_*HEADS_/4,256,0,stream>>>(qkvh);
    kvprep<<<B_*NKEY_/4,256,0,stream>>>(qkvh, nkv + (size_t)l*2*DH_, kh, vh);
    attn_mfma<<<dim3(9,HEADS_,B_),256,0,stream>>>(qkvh, kh, vh, biasd, oh);
    gemm_bf16<0><<<dim3(6,33),256,0,stream>>>(oh, WoT + (size_t)l*DIM_*DIM_, NROW_, DIM_, DIM_,
                                              tb, nullptr, nullptr, 0, 0);
    ln_resid<<<NROW_,256,0,stream>>>(tb, aoutg + (size_t)l*DIM_, x);
    ln_to_bf16<<<NROW_,256,0,stream>>>(x, fng + (size_t)l*DIM_, xnh, 0);
    gemm_bf16<1><<<dim3(48,33),256,0,stream>>>(xnh, WinP + (size_t)l*DIM_*2*FFI_, NROW_, FFI_, DIM_,
                                               nullptr, ub, nullptr, 3, 0);
    gemm_bf16<0><<<dim3(6,33),256,0,stream>>>(ub, WoutT + (size_t)l*FFI_*DIM_, NROW_, DIM_, FFI_,
                                              nullptr, nullptr, x, 2, 0);
  }

  ln_to_bf16<<<NROW_,256,0,stream>>>(x, fing, xnh, 1);
  gemm_bf16<0><<<dim3(6,17),256,0,stream>>>(xnh, WprojT, B_*NT_, DIM_, DIM_,
                                            out, nullptr, nullptr, 0, 1);
}